// Round 11
// baseline (409.642 us; speedup 1.0000x reference)
//
#include <hip/hip_runtime.h>
#include <math.h>

#define TPB 256
#define SC_TPB 256
#define SC_ITEMS 8   // 2048 elements per scan block
#define CH 8192      // edges per bucket-pass block
#define BKT 512      // nodes per bucket (bucket = dst >> 9)

// ---------------- multi-block exclusive scan (2 kernels) ----------------

__global__ __launch_bounds__(SC_TPB) void k_scan_blocks(const int* __restrict__ cnt,
                                                        int* __restrict__ bsum, int n) {
    __shared__ int red[SC_TPB / 64];
    int base = blockIdx.x * SC_TPB * SC_ITEMS;
    int s = 0;
    for (int it = 0; it < SC_ITEMS; ++it) {
        int i = base + it * SC_TPB + threadIdx.x;
        if (i < n) s += cnt[i];
    }
    for (int d = 1; d < 64; d <<= 1) s += __shfl_xor(s, d);
    if ((threadIdx.x & 63) == 0) red[threadIdx.x >> 6] = s;
    __syncthreads();
    if (threadIdx.x == 0) {
        int t = 0;
        for (int w = 0; w < SC_TPB / 64; ++w) t += red[w];
        bsum[blockIdx.x] = t;
    }
}

// final scan pass; computes its own block-prefix from raw bsum (<=64 entries);
// emits bkst[b] = scanned[b*nblk]; block 0 writes off[N]=E, bkst[NB]=E.
__global__ __launch_bounds__(SC_TPB) void k_scan_final(const int* __restrict__ cnt,
                                                       const int* __restrict__ bsum,
                                                       int* __restrict__ off,
                                                       int* __restrict__ bkst, int nblk,
                                                       int n, int total,
                                                       int* __restrict__ off_n,
                                                       int* __restrict__ bkst_n) {
    __shared__ int wsum[SC_TPB / 64];
    int bpref = 0;
    for (int i = 0; i < (int)blockIdx.x; ++i) bpref += bsum[i];  // uniform, <=64 iters
    int base = blockIdx.x * SC_TPB * SC_ITEMS;
    int tbase = base + threadIdx.x * SC_ITEMS;
    int loc[SC_ITEMS];
    int s = 0;
    for (int it = 0; it < SC_ITEMS; ++it) {
        int i = tbase + it;
        int v = (i < n) ? cnt[i] : 0;
        loc[it] = s;
        s += v;
    }
    int l = threadIdx.x & 63, wv = threadIdx.x >> 6;
    int inc = s;
    for (int d = 1; d < 64; d <<= 1) {
        int t = __shfl_up(inc, d);
        if (l >= d) inc += t;
    }
    int thr_ex = inc - s;
    if (l == 63) wsum[wv] = inc;
    __syncthreads();
    int woff = 0;
    for (int w = 0; w < wv; ++w) woff += wsum[w];
    int pref = bpref + woff + thr_ex;
    for (int it = 0; it < SC_ITEMS; ++it) {
        int i = tbase + it;
        if (i < n) {
            int val = pref + loc[it];
            off[i] = val;
            if (i % nblk == 0) bkst[i / nblk] = val;
        }
    }
    if (blockIdx.x == 0 && threadIdx.x == 0) { *off_n = total; *bkst_n = total; }
}

// ---------------- bucket pass 1: per-(bucket, block) counts, LDS histogram ----------------

__global__ __launch_bounds__(256) void k_bucket_count(const int* __restrict__ dst,
                                                      int* __restrict__ M,
                                                      int e, int nb, int nblk) {
    __shared__ int h[256];  // nb <= 256 (N <= 131072)
    for (int i = threadIdx.x; i < nb; i += 256) h[i] = 0;
    __syncthreads();
    int base = blockIdx.x * CH;
    int lim = min(base + CH, e);
    for (int i = base + threadIdx.x; i < lim; i += 256)
        atomicAdd(&h[dst[i] >> 9], 1);
    __syncthreads();
    for (int b = threadIdx.x; b < nb; b += 256)
        M[b * nblk + blockIdx.x] = h[b];
}

// ---------------- bucket pass 2: scatter packed edges into bucket regions ----------------
// packed: src (17 bits, N<=131072) | dst_local (9 bits) << 17

__global__ __launch_bounds__(256) void k_bucket_scatter(const int* __restrict__ src,
                                                        const int* __restrict__ dst,
                                                        const float* __restrict__ w,
                                                        const int* __restrict__ Ms,
                                                        int2* __restrict__ barr,
                                                        int e, int nb, int nblk) {
    __shared__ int cur[256];
    for (int i = threadIdx.x; i < nb; i += 256) cur[i] = Ms[i * nblk + blockIdx.x];
    __syncthreads();
    int base = blockIdx.x * CH;
    int lim = min(base + CH, e);
    for (int i = base + threadIdx.x; i < lim; i += 256) {
        int d = dst[i];
        int p = atomicAdd(&cur[d >> 9], 1);  // LDS cursor
        barr[p] = make_int2(src[i] | ((d & 511) << 17), __float_as_int(w[i]));
    }
}

// ---------------- bucket pass 3: per-bucket CSR build + degree/dis ----------------

__global__ __launch_bounds__(256) void k_csr_build(const int2* __restrict__ barr,
                                                   const int* __restrict__ bucketStart,
                                                   float* __restrict__ dis,
                                                   int* __restrict__ off,
                                                   int* __restrict__ srcs,
                                                   float* __restrict__ wtmp, int n) {
    int b = blockIdx.x;
    int nbase = b << 9;
    int ebeg = bucketStart[b], eend = bucketStart[b + 1];
    __shared__ int cnt[BKT];
    __shared__ float wsum[BKT];
    __shared__ float disL[BKT];
    __shared__ int scn[BKT];
    __shared__ int wtot[4];

    for (int i = threadIdx.x; i < BKT; i += 256) { cnt[i] = 0; wsum[i] = 0.f; }
    __syncthreads();
    for (int j = ebeg + threadIdx.x; j < eend; j += 256) {
        int2 ed = barr[j];
        int dl = ed.x >> 17;
        atomicAdd(&cnt[dl], 1);
        atomicAdd(&wsum[dl], __int_as_float(ed.y));
    }
    __syncthreads();

    int t = threadIdx.x;
    int a0 = cnt[2 * t], a1 = cnt[2 * t + 1];
    int s = a0 + a1;
    int l = t & 63, wv = t >> 6;
    int inc = s;
    for (int d = 1; d < 64; d <<= 1) {
        int u = __shfl_up(inc, d);
        if (l >= d) inc += u;
    }
    if (l == 63) wtot[wv] = inc;
    for (int i = threadIdx.x; i < BKT; i += 256) {
        int node = nbase + i;
        if (node < n) {
            float dv = rsqrtf(1.0f + wsum[i]);  // deg = 1 (self-loop) + sum(w) > 0
            disL[i] = dv;
            dis[node] = dv;
        }
    }
    __syncthreads();
    int woff = 0;
    for (int k = 0; k < wv; ++k) woff += wtot[k];
    int ex = woff + inc - s;
    scn[2 * t] = ex;
    scn[2 * t + 1] = ex + a0;
    __syncthreads();
    for (int i = threadIdx.x; i < BKT; i += 256) {
        int node = nbase + i;
        if (node < n) off[node] = ebeg + scn[i];
    }
    __syncthreads();
    for (int j = ebeg + threadIdx.x; j < eend; j += 256) {
        int2 ed = barr[j];
        int dl = ed.x >> 17;
        int p = ebeg + atomicAdd(&scn[dl], 1);
        srcs[p] = ed.x & 0x1FFFF;
        wtmp[p] = __int_as_float(ed.y) * disL[dl];  // w * dis[dst]; dis[src] applied in gather
    }
}

// ---------------- dense GEMM  Y[n,C] = X[n,K] @ W[K,C]  (layer 1 only, R8 version) ----------------

template <int K, int C, bool RELU>
__global__ __launch_bounds__(256) void k_gemm(const float* __restrict__ X,
                                              const float* __restrict__ W,
                                              float* __restrict__ Y, int n) {
    constexpr int CPT = (C == 32) ? 4 : 8;
    constexpr int CG = C / CPT;            // 8
    constexpr int RG = 256 / CG;           // 32
    constexpr int M = RG * 4;              // 128 rows per block
    constexpr int KC = (K > 64) ? 64 : K;  // K chunk
    constexpr int NKB = KC / 4;            // 16B k-blocks per chunk

    __shared__ float Ws[KC * C];
    __shared__ float Xs[M * KC];

    const int cg = threadIdx.x & (CG - 1);
    const int rg = threadIdx.x / CG;
    const int c0 = cg * CPT;
    const int r0 = rg * 4;
    const int base = blockIdx.x * M;

    float acc[4][CPT];
#pragma unroll
    for (int i = 0; i < 4; ++i)
#pragma unroll
        for (int j = 0; j < CPT; ++j) acc[i][j] = 0.f;

    for (int kc = 0; kc < K; kc += KC) {
        if (kc) __syncthreads();
        const float4* Wg4 = (const float4*)(W + (size_t)kc * C);
        for (int v = threadIdx.x; v < KC * C / 4; v += 256)
            ((float4*)Ws)[v] = Wg4[v];
        for (int v = threadIdx.x; v < M * NKB; v += 256) {
            int m = v / NKB, kb = v % NKB;
            int row = base + m;
            float4 val = make_float4(0.f, 0.f, 0.f, 0.f);
            if (row < n) val = *(const float4*)(X + (size_t)row * K + kc + kb * 4);
            if (RELU) {
                val.x = fmaxf(val.x, 0.f); val.y = fmaxf(val.y, 0.f);
                val.z = fmaxf(val.z, 0.f); val.w = fmaxf(val.w, 0.f);
            }
            *(float4*)&Xs[m * KC + ((kb ^ (m & 3)) << 2)] = val;
        }
        __syncthreads();

#pragma unroll 1
        for (int kb = 0; kb < NKB; ++kb) {
            const int k = kb * 4;
            float4 xv[4];
#pragma unroll
            for (int i = 0; i < 4; ++i)
                xv[i] = *(const float4*)&Xs[(r0 + i) * KC + ((kb ^ i) << 2)];
#pragma unroll
            for (int kk = 0; kk < 4; ++kk) {
                float4 wa = *(const float4*)&Ws[(k + kk) * C + c0];
                float4 wb;
                if constexpr (CPT == 8)
                    wb = *(const float4*)&Ws[(k + kk) * C + c0 + 4];
#pragma unroll
                for (int i = 0; i < 4; ++i) {
                    float xk = ((const float*)&xv[i])[kk];
                    acc[i][0] = fmaf(xk, wa.x, acc[i][0]);
                    acc[i][1] = fmaf(xk, wa.y, acc[i][1]);
                    acc[i][2] = fmaf(xk, wa.z, acc[i][2]);
                    acc[i][3] = fmaf(xk, wa.w, acc[i][3]);
                    if constexpr (CPT == 8) {
                        acc[i][4] = fmaf(xk, wb.x, acc[i][4]);
                        acc[i][5] = fmaf(xk, wb.y, acc[i][5]);
                        acc[i][6] = fmaf(xk, wb.z, acc[i][6]);
                        acc[i][7] = fmaf(xk, wb.w, acc[i][7]);
                    }
                }
            }
        }
    }

#pragma unroll
    for (int i = 0; i < 4; ++i) {
        int row = base + r0 + i;
        if (row < n) {
            *(float4*)(Y + (size_t)row * C + c0) =
                make_float4(acc[i][0], acc[i][1], acc[i][2], acc[i][3]);
            if constexpr (CPT == 8)
                *(float4*)(Y + (size_t)row * C + c0 + 4) =
                    make_float4(acc[i][4], acc[i][5], acc[i][6], acc[i][7]);
        }
    }
}

// ---------------- fused gather(64ch) + relu + GEMM(64->CO)  (R8 config + NT edge streams) ----
// Block = 64 nodes. Phase 1: 16 quarter-waves (16 lanes, float4 = 256B/row),
// 4 nodes each, unroll-4 edge loop -> Ys[64][64] XOR-swizzled in 16B blocks.
// Phase 2: 256 threads, rows {rg, rg+32} x CPT cols, W staged in LDS.
// Edge streams (srcs/wtmp) loaded non-temporally to avoid evicting table rows from L2.

template <int CO>
__global__ __launch_bounds__(256) void k_gg(const float* __restrict__ HW,
                                            const int* __restrict__ off,
                                            const int* __restrict__ srcs,
                                            const float* __restrict__ wtmp,
                                            const float* __restrict__ dis,
                                            const float* __restrict__ bias,
                                            const float* __restrict__ W,
                                            float* __restrict__ Yout, int n) {
    __shared__ float Ys[64 * 64];
    __shared__ float Ws[64 * CO];

    const int base = blockIdx.x * 64;

    // stage W (64 x CO)
    for (int v = threadIdx.x; v < 64 * CO / 4; v += 256)
        ((float4*)Ws)[v] = ((const float4*)W)[v];

    // phase 1: 16 quarter-waves x 4 nodes
    {
        const int qw = threadIdx.x >> 4;
        const int l = threadIdx.x & 15;
        const float4* HW4 = (const float4*)HW;
        const float4 bb = ((const float4*)bias)[l];
#pragma unroll 1
        for (int p = 0; p < 4; ++p) {
            int m = qw * 4 + p;
            int node = base + m;
            if (node < n) {
                float dd = dis[node];
                float4 hv = HW4[node * 16 + l];
                float4 A0, A1, A2, A3;
                A0.x = fmaf(dd * dd, hv.x, bb.x);
                A0.y = fmaf(dd * dd, hv.y, bb.y);
                A0.z = fmaf(dd * dd, hv.z, bb.z);
                A0.w = fmaf(dd * dd, hv.w, bb.w);
                A1 = make_float4(0.f, 0.f, 0.f, 0.f);
                A2 = A1; A3 = A1;
                int j = off[node], end = off[node + 1];
                for (; j + 3 < end; j += 4) {
                    int s0 = __builtin_nontemporal_load(srcs + j);
                    int s1 = __builtin_nontemporal_load(srcs + j + 1);
                    int s2 = __builtin_nontemporal_load(srcs + j + 2);
                    int s3 = __builtin_nontemporal_load(srcs + j + 3);
                    float w0 = __builtin_nontemporal_load(wtmp + j) * dis[s0];
                    float w1 = __builtin_nontemporal_load(wtmp + j + 1) * dis[s1];
                    float w2 = __builtin_nontemporal_load(wtmp + j + 2) * dis[s2];
                    float w3 = __builtin_nontemporal_load(wtmp + j + 3) * dis[s3];
                    float4 v0 = HW4[s0 * 16 + l];
                    float4 v1 = HW4[s1 * 16 + l];
                    float4 v2 = HW4[s2 * 16 + l];
                    float4 v3 = HW4[s3 * 16 + l];
                    A0.x = fmaf(w0, v0.x, A0.x); A0.y = fmaf(w0, v0.y, A0.y);
                    A0.z = fmaf(w0, v0.z, A0.z); A0.w = fmaf(w0, v0.w, A0.w);
                    A1.x = fmaf(w1, v1.x, A1.x); A1.y = fmaf(w1, v1.y, A1.y);
                    A1.z = fmaf(w1, v1.z, A1.z); A1.w = fmaf(w1, v1.w, A1.w);
                    A2.x = fmaf(w2, v2.x, A2.x); A2.y = fmaf(w2, v2.y, A2.y);
                    A2.z = fmaf(w2, v2.z, A2.z); A2.w = fmaf(w2, v2.w, A2.w);
                    A3.x = fmaf(w3, v3.x, A3.x); A3.y = fmaf(w3, v3.y, A3.y);
                    A3.z = fmaf(w3, v3.z, A3.z); A3.w = fmaf(w3, v3.w, A3.w);
                }
                for (; j < end; ++j) {
                    int s0 = __builtin_nontemporal_load(srcs + j);
                    float w0 = __builtin_nontemporal_load(wtmp + j) * dis[s0];
                    float4 v0 = HW4[s0 * 16 + l];
                    A0.x = fmaf(w0, v0.x, A0.x); A0.y = fmaf(w0, v0.y, A0.y);
                    A0.z = fmaf(w0, v0.z, A0.z); A0.w = fmaf(w0, v0.w, A0.w);
                }
                float4 o;
                o.x = fmaxf((A0.x + A1.x) + (A2.x + A3.x), 0.f);
                o.y = fmaxf((A0.y + A1.y) + (A2.y + A3.y), 0.f);
                o.z = fmaxf((A0.z + A1.z) + (A2.z + A3.z), 0.f);
                o.w = fmaxf((A0.w + A1.w) + (A2.w + A3.w), 0.f);
                *(float4*)&Ys[m * 64 + ((l ^ (m & 7)) << 2)] = o;   // swizzled 16B block
            }
        }
    }
    __syncthreads();

    // phase 2: Yout[64][CO] = Ys @ Ws ; thread tile = rows {rg, rg+32} x CPT
    constexpr int CPT = (CO == 32) ? 4 : 8;
    const int cg = threadIdx.x & 7;       // 8 col groups
    const int rg = threadIdx.x >> 3;      // 0..31
    const int c0 = cg * CPT;
    const int sw = rg & 7;                // row&7, same for rg and rg+32

    float acc[2][CPT];
#pragma unroll
    for (int i = 0; i < 2; ++i)
#pragma unroll
        for (int j = 0; j < CPT; ++j) acc[i][j] = 0.f;

#pragma unroll 1
    for (int kb = 0; kb < 16; ++kb) {
        const int k = kb * 4;
        float4 xv0 = *(const float4*)&Ys[rg * 64 + ((kb ^ sw) << 2)];
        float4 xv1 = *(const float4*)&Ys[(rg + 32) * 64 + ((kb ^ sw) << 2)];
#pragma unroll
        for (int kk = 0; kk < 4; ++kk) {
            float4 wa = *(const float4*)&Ws[(k + kk) * CO + c0];
            float4 wb;
            if constexpr (CPT == 8)
                wb = *(const float4*)&Ws[(k + kk) * CO + c0 + 4];
            float x0 = ((const float*)&xv0)[kk];
            float x1 = ((const float*)&xv1)[kk];
            acc[0][0] = fmaf(x0, wa.x, acc[0][0]); acc[1][0] = fmaf(x1, wa.x, acc[1][0]);
            acc[0][1] = fmaf(x0, wa.y, acc[0][1]); acc[1][1] = fmaf(x1, wa.y, acc[1][1]);
            acc[0][2] = fmaf(x0, wa.z, acc[0][2]); acc[1][2] = fmaf(x1, wa.z, acc[1][2]);
            acc[0][3] = fmaf(x0, wa.w, acc[0][3]); acc[1][3] = fmaf(x1, wa.w, acc[1][3]);
            if constexpr (CPT == 8) {
                acc[0][4] = fmaf(x0, wb.x, acc[0][4]); acc[1][4] = fmaf(x1, wb.x, acc[1][4]);
                acc[0][5] = fmaf(x0, wb.y, acc[0][5]); acc[1][5] = fmaf(x1, wb.y, acc[1][5]);
                acc[0][6] = fmaf(x0, wb.z, acc[0][6]); acc[1][6] = fmaf(x1, wb.z, acc[1][6]);
                acc[0][7] = fmaf(x0, wb.w, acc[0][7]); acc[1][7] = fmaf(x1, wb.w, acc[1][7]);
            }
        }
    }

#pragma unroll
    for (int i = 0; i < 2; ++i) {
        int row = base + rg + 32 * i;
        if (row < n) {
            *(float4*)(Yout + (size_t)row * CO + c0) =
                make_float4(acc[i][0], acc[i][1], acc[i][2], acc[i][3]);
            if constexpr (CPT == 8)
                *(float4*)(Yout + (size_t)row * CO + c0 + 4) =
                    make_float4(acc[i][4], acc[i][5], acc[i][6], acc[i][7]);
        }
    }
}

// ---------------- final CSR gather (32ch), quarter-wave float2, NT streams ----------------

__global__ __launch_bounds__(TPB) void k_gather32(const float* __restrict__ HW,
                                                  const int* __restrict__ off,
                                                  const int* __restrict__ srcs,
                                                  const float* __restrict__ wtmp,
                                                  const float* __restrict__ dis,
                                                  const float* __restrict__ b,
                                                  float* __restrict__ Y, int n) {
    int node = (blockIdx.x * blockDim.x + threadIdx.x) >> 4;
    int l = threadIdx.x & 15;
    if (node >= n) return;
    const float2* HW2 = (const float2*)HW;
    float dd = dis[node];
    float2 hv = HW2[node * 16 + l];
    float2 bb = ((const float2*)b)[l];
    float a0x = fmaf(dd * dd, hv.x, bb.x);
    float a0y = fmaf(dd * dd, hv.y, bb.y);
    float a1x = 0.f, a1y = 0.f, a2x = 0.f, a2y = 0.f, a3x = 0.f, a3y = 0.f;
    int j = off[node], end = off[node + 1];
    for (; j + 3 < end; j += 4) {
        int s0 = __builtin_nontemporal_load(srcs + j);
        int s1 = __builtin_nontemporal_load(srcs + j + 1);
        int s2 = __builtin_nontemporal_load(srcs + j + 2);
        int s3 = __builtin_nontemporal_load(srcs + j + 3);
        float w0 = __builtin_nontemporal_load(wtmp + j) * dis[s0];
        float w1 = __builtin_nontemporal_load(wtmp + j + 1) * dis[s1];
        float w2 = __builtin_nontemporal_load(wtmp + j + 2) * dis[s2];
        float w3 = __builtin_nontemporal_load(wtmp + j + 3) * dis[s3];
        float2 v0 = HW2[s0 * 16 + l];
        float2 v1 = HW2[s1 * 16 + l];
        float2 v2 = HW2[s2 * 16 + l];
        float2 v3 = HW2[s3 * 16 + l];
        a0x = fmaf(w0, v0.x, a0x); a0y = fmaf(w0, v0.y, a0y);
        a1x = fmaf(w1, v1.x, a1x); a1y = fmaf(w1, v1.y, a1y);
        a2x = fmaf(w2, v2.x, a2x); a2y = fmaf(w2, v2.y, a2y);
        a3x = fmaf(w3, v3.x, a3x); a3y = fmaf(w3, v3.y, a3y);
    }
    for (; j < end; ++j) {
        int s0 = __builtin_nontemporal_load(srcs + j);
        float w0 = __builtin_nontemporal_load(wtmp + j) * dis[s0];
        float2 v0 = HW2[s0 * 16 + l];
        a0x = fmaf(w0, v0.x, a0x); a0y = fmaf(w0, v0.y, a0y);
    }
    float* yp = Y + (size_t)node * 32 + l * 2;
    __builtin_nontemporal_store((a0x + a1x) + (a2x + a3x), yp);
    __builtin_nontemporal_store((a0y + a1y) + (a2y + a3y), yp + 1);
}

// ---------------- launch ----------------

extern "C" void kernel_launch(void* const* d_in, const int* in_sizes, int n_in,
                              void* d_out, int out_size, void* d_ws, size_t ws_size,
                              hipStream_t stream) {
    const float* x  = (const float*)d_in[0];
    const int*   ei = (const int*)d_in[1];
    const float* ew = (const float*)d_in[2];
    const float* W1 = (const float*)d_in[3];
    const float* b1 = (const float*)d_in[4];
    const float* W2 = (const float*)d_in[5];
    const float* b2 = (const float*)d_in[6];
    const float* W3 = (const float*)d_in[7];
    const float* b3 = (const float*)d_in[8];
    float* out = (float*)d_out;

    const int IN_C = 128, HID_C = 64;
    const int N = in_sizes[0] / IN_C;   // 100000 (< 2^17, required by packing)
    const int E = in_sizes[2];          // 1600000

    const int* src = ei;       // edge_index[0] = row (gather source)
    const int* dst = ei + E;   // edge_index[1] = col (destination)

    const int NB   = (N + BKT - 1) / BKT;        // 196 buckets (<=256 required)
    const int NBLK = (E + CH - 1) / CH;          // 196 chunk-blocks
    const int LM   = NB * NBLK;                  // count-matrix size

    // ---- workspace layout ----
    char* w = (char*)d_ws;
    float* dis   = (float*)w;                 w += sizeof(float) * N;
    int*   off   = (int*)w;                   w += sizeof(int) * (N + 1);
    int*   bkst  = (int*)w;                   w += sizeof(int) * (NB + 1);
    int*   bsum  = (int*)w;                   w += sizeof(int) * 64;
    int*   srcs  = (int*)w;                   w += sizeof(int) * E;
    float* wtmp  = (float*)w;                 w += sizeof(float) * E;
    // transient region: [M | barr] overlapped later by [A | B]
    char* w2 = (char*)(((size_t)w + 15) & ~(size_t)15);
    int*  M    = (int*)w2;
    int2* barr = (int2*)(((size_t)(M + LM) + 15) & ~(size_t)15);   // E int2
    float* A   = (float*)w2;                                       // N*64 (also A3: N*32)
    float* B   = A + (size_t)N * HID_C;                            // N*64

    const int nScanM = (LM + SC_TPB * SC_ITEMS - 1) / (SC_TPB * SC_ITEMS);  // 19 <= 64

    // ---- build CSR + normalization (no global atomics) ----
    k_bucket_count<<<NBLK, 256, 0, stream>>>(dst, M, E, NB, NBLK);
    k_scan_blocks<<<nScanM, SC_TPB, 0, stream>>>(M, bsum, LM);
    k_scan_final<<<nScanM, SC_TPB, 0, stream>>>(M, bsum, M, bkst, NBLK, LM, E,
                                                off + N, bkst + NB);
    k_bucket_scatter<<<NBLK, 256, 0, stream>>>(src, dst, ew, M, barr, E, NB, NBLK);
    k_csr_build<<<NB, 256, 0, stream>>>(barr, bkst, dis, off, srcs, wtmp, N);

    const int nT128 = (N + 127) / 128;
    const int nT64  = (N + 63) / 64;
    const int gQ    = (N * 16 + TPB - 1) / TPB;   // quarter-wave per node

    // ---- layer 1 GEMM: A = x @ W1 ----
    k_gemm<128, 64, false><<<nT128, 256, 0, stream>>>(x, W1, A, N);
    // ---- fused: B = relu(agg(A) + b1) @ W2 ----
    k_gg<64><<<nT64, 256, 0, stream>>>(A, off, srcs, wtmp, dis, b1, W2, B, N);
    // ---- fused: A3 = relu(agg(B) + b2) @ W3  (A3 reuses A region, N*32) ----
    k_gg<32><<<nT64, 256, 0, stream>>>(B, off, srcs, wtmp, dis, b2, W3, A, N);
    // ---- final: out = agg(A3) + b3 ----
    k_gather32<<<gQ, TPB, 0, stream>>>(A, off, srcs, wtmp, dis, b3, out, N);
}

// Round 12
// 366.473 us; speedup vs baseline: 1.1178x; 1.1178x over previous
//
#include <hip/hip_runtime.h>
#include <math.h>

#define TPB 256
#define SC_TPB 256
#define SC_ITEMS 8   // 2048 elements per scan block
#define CH 8192      // edges per bucket-pass block
#define BKT 512      // nodes per bucket (bucket = dst >> 9)

// ---------------- multi-block exclusive scan (2 kernels) ----------------

__global__ __launch_bounds__(SC_TPB) void k_scan_blocks(const int* __restrict__ cnt,
                                                        int* __restrict__ bsum, int n) {
    __shared__ int red[SC_TPB / 64];
    int base = blockIdx.x * SC_TPB * SC_ITEMS;
    int s = 0;
    for (int it = 0; it < SC_ITEMS; ++it) {
        int i = base + it * SC_TPB + threadIdx.x;
        if (i < n) s += cnt[i];
    }
    for (int d = 1; d < 64; d <<= 1) s += __shfl_xor(s, d);
    if ((threadIdx.x & 63) == 0) red[threadIdx.x >> 6] = s;
    __syncthreads();
    if (threadIdx.x == 0) {
        int t = 0;
        for (int w = 0; w < SC_TPB / 64; ++w) t += red[w];
        bsum[blockIdx.x] = t;
    }
}

// final scan pass; computes its own block-prefix from raw bsum (<=64 entries);
// emits bkst[b] = scanned[b*nblk]; block 0 writes off[N]=E, bkst[NB]=E.
__global__ __launch_bounds__(SC_TPB) void k_scan_final(const int* __restrict__ cnt,
                                                       const int* __restrict__ bsum,
                                                       int* __restrict__ off,
                                                       int* __restrict__ bkst, int nblk,
                                                       int n, int total,
                                                       int* __restrict__ off_n,
                                                       int* __restrict__ bkst_n) {
    __shared__ int wsum[SC_TPB / 64];
    int bpref = 0;
    for (int i = 0; i < (int)blockIdx.x; ++i) bpref += bsum[i];  // uniform, <=64 iters
    int base = blockIdx.x * SC_TPB * SC_ITEMS;
    int tbase = base + threadIdx.x * SC_ITEMS;
    int loc[SC_ITEMS];
    int s = 0;
    for (int it = 0; it < SC_ITEMS; ++it) {
        int i = tbase + it;
        int v = (i < n) ? cnt[i] : 0;
        loc[it] = s;
        s += v;
    }
    int l = threadIdx.x & 63, wv = threadIdx.x >> 6;
    int inc = s;
    for (int d = 1; d < 64; d <<= 1) {
        int t = __shfl_up(inc, d);
        if (l >= d) inc += t;
    }
    int thr_ex = inc - s;
    if (l == 63) wsum[wv] = inc;
    __syncthreads();
    int woff = 0;
    for (int w = 0; w < wv; ++w) woff += wsum[w];
    int pref = bpref + woff + thr_ex;
    for (int it = 0; it < SC_ITEMS; ++it) {
        int i = tbase + it;
        if (i < n) {
            int val = pref + loc[it];
            off[i] = val;
            if (i % nblk == 0) bkst[i / nblk] = val;
        }
    }
    if (blockIdx.x == 0 && threadIdx.x == 0) { *off_n = total; *bkst_n = total; }
}

// ---------------- bucket pass 1: per-(bucket, block) counts, LDS histogram ----------------

__global__ __launch_bounds__(256) void k_bucket_count(const int* __restrict__ dst,
                                                      int* __restrict__ M,
                                                      int e, int nb, int nblk) {
    __shared__ int h[256];  // nb <= 256 (N <= 131072)
    for (int i = threadIdx.x; i < nb; i += 256) h[i] = 0;
    __syncthreads();
    int base = blockIdx.x * CH;
    int lim = min(base + CH, e);
    for (int i = base + threadIdx.x; i < lim; i += 256)
        atomicAdd(&h[dst[i] >> 9], 1);
    __syncthreads();
    for (int b = threadIdx.x; b < nb; b += 256)
        M[b * nblk + blockIdx.x] = h[b];
}

// ---------------- bucket pass 2: scatter packed edges into bucket regions ----------------
// packed: src (17 bits, N<=131072) | dst_local (9 bits) << 17

__global__ __launch_bounds__(256) void k_bucket_scatter(const int* __restrict__ src,
                                                        const int* __restrict__ dst,
                                                        const float* __restrict__ w,
                                                        const int* __restrict__ Ms,
                                                        int2* __restrict__ barr,
                                                        int e, int nb, int nblk) {
    __shared__ int cur[256];
    for (int i = threadIdx.x; i < nb; i += 256) cur[i] = Ms[i * nblk + blockIdx.x];
    __syncthreads();
    int base = blockIdx.x * CH;
    int lim = min(base + CH, e);
    for (int i = base + threadIdx.x; i < lim; i += 256) {
        int d = dst[i];
        int p = atomicAdd(&cur[d >> 9], 1);  // LDS cursor
        barr[p] = make_int2(src[i] | ((d & 511) << 17), __float_as_int(w[i]));
    }
}

// ---------------- bucket pass 3: per-bucket CSR build + degree/dis ----------------
// Emits ewn[p] = {src, w * dis[dst]} (int2); dis[src] folded in by k_finw.

__global__ __launch_bounds__(256) void k_csr_build(const int2* __restrict__ barr,
                                                   const int* __restrict__ bucketStart,
                                                   float* __restrict__ dis,
                                                   int* __restrict__ off,
                                                   int2* __restrict__ ewn, int n) {
    int b = blockIdx.x;
    int nbase = b << 9;
    int ebeg = bucketStart[b], eend = bucketStart[b + 1];
    __shared__ int cnt[BKT];
    __shared__ float wsum[BKT];
    __shared__ float disL[BKT];
    __shared__ int scn[BKT];
    __shared__ int wtot[4];

    for (int i = threadIdx.x; i < BKT; i += 256) { cnt[i] = 0; wsum[i] = 0.f; }
    __syncthreads();
    for (int j = ebeg + threadIdx.x; j < eend; j += 256) {
        int2 ed = barr[j];
        int dl = ed.x >> 17;
        atomicAdd(&cnt[dl], 1);
        atomicAdd(&wsum[dl], __int_as_float(ed.y));
    }
    __syncthreads();

    int t = threadIdx.x;
    int a0 = cnt[2 * t], a1 = cnt[2 * t + 1];
    int s = a0 + a1;
    int l = t & 63, wv = t >> 6;
    int inc = s;
    for (int d = 1; d < 64; d <<= 1) {
        int u = __shfl_up(inc, d);
        if (l >= d) inc += u;
    }
    if (l == 63) wtot[wv] = inc;
    for (int i = threadIdx.x; i < BKT; i += 256) {
        int node = nbase + i;
        if (node < n) {
            float dv = rsqrtf(1.0f + wsum[i]);  // deg = 1 (self-loop) + sum(w) > 0
            disL[i] = dv;
            dis[node] = dv;
        }
    }
    __syncthreads();
    int woff = 0;
    for (int k = 0; k < wv; ++k) woff += wtot[k];
    int ex = woff + inc - s;
    scn[2 * t] = ex;
    scn[2 * t + 1] = ex + a0;
    __syncthreads();
    for (int i = threadIdx.x; i < BKT; i += 256) {
        int node = nbase + i;
        if (node < n) off[node] = ebeg + scn[i];
    }
    __syncthreads();
    for (int j = ebeg + threadIdx.x; j < eend; j += 256) {
        int2 ed = barr[j];
        int dl = ed.x >> 17;
        int p = ebeg + atomicAdd(&scn[dl], 1);
        ewn[p] = make_int2(ed.x & 0x1FFFF,
                           __float_as_int(__int_as_float(ed.y) * disL[dl]));
    }
}

// fold dis[src] into the edge weight: ewn[i].y = w * dis[dst] * dis[src]
__global__ void k_finw(int2* __restrict__ ewn, const float* __restrict__ dis, int e) {
    int i = blockIdx.x * blockDim.x + threadIdx.x;
    if (i < e) {
        int2 v = ewn[i];
        ewn[i].y = __float_as_int(__int_as_float(v.y) * dis[v.x]);
    }
}

// ---------------- dense GEMM  Y[n,C] = X[n,K] @ W[K,C]  (layer 1 only, R8 version) ----------------

template <int K, int C, bool RELU>
__global__ __launch_bounds__(256) void k_gemm(const float* __restrict__ X,
                                              const float* __restrict__ W,
                                              float* __restrict__ Y, int n) {
    constexpr int CPT = (C == 32) ? 4 : 8;
    constexpr int CG = C / CPT;            // 8
    constexpr int RG = 256 / CG;           // 32
    constexpr int M = RG * 4;              // 128 rows per block
    constexpr int KC = (K > 64) ? 64 : K;  // K chunk
    constexpr int NKB = KC / 4;            // 16B k-blocks per chunk

    __shared__ float Ws[KC * C];
    __shared__ float Xs[M * KC];

    const int cg = threadIdx.x & (CG - 1);
    const int rg = threadIdx.x / CG;
    const int c0 = cg * CPT;
    const int r0 = rg * 4;
    const int base = blockIdx.x * M;

    float acc[4][CPT];
#pragma unroll
    for (int i = 0; i < 4; ++i)
#pragma unroll
        for (int j = 0; j < CPT; ++j) acc[i][j] = 0.f;

    for (int kc = 0; kc < K; kc += KC) {
        if (kc) __syncthreads();
        const float4* Wg4 = (const float4*)(W + (size_t)kc * C);
        for (int v = threadIdx.x; v < KC * C / 4; v += 256)
            ((float4*)Ws)[v] = Wg4[v];
        for (int v = threadIdx.x; v < M * NKB; v += 256) {
            int m = v / NKB, kb = v % NKB;
            int row = base + m;
            float4 val = make_float4(0.f, 0.f, 0.f, 0.f);
            if (row < n) val = *(const float4*)(X + (size_t)row * K + kc + kb * 4);
            if (RELU) {
                val.x = fmaxf(val.x, 0.f); val.y = fmaxf(val.y, 0.f);
                val.z = fmaxf(val.z, 0.f); val.w = fmaxf(val.w, 0.f);
            }
            *(float4*)&Xs[m * KC + ((kb ^ (m & 3)) << 2)] = val;
        }
        __syncthreads();

#pragma unroll 1
        for (int kb = 0; kb < NKB; ++kb) {
            const int k = kb * 4;
            float4 xv[4];
#pragma unroll
            for (int i = 0; i < 4; ++i)
                xv[i] = *(const float4*)&Xs[(r0 + i) * KC + ((kb ^ i) << 2)];
#pragma unroll
            for (int kk = 0; kk < 4; ++kk) {
                float4 wa = *(const float4*)&Ws[(k + kk) * C + c0];
                float4 wb;
                if constexpr (CPT == 8)
                    wb = *(const float4*)&Ws[(k + kk) * C + c0 + 4];
#pragma unroll
                for (int i = 0; i < 4; ++i) {
                    float xk = ((const float*)&xv[i])[kk];
                    acc[i][0] = fmaf(xk, wa.x, acc[i][0]);
                    acc[i][1] = fmaf(xk, wa.y, acc[i][1]);
                    acc[i][2] = fmaf(xk, wa.z, acc[i][2]);
                    acc[i][3] = fmaf(xk, wa.w, acc[i][3]);
                    if constexpr (CPT == 8) {
                        acc[i][4] = fmaf(xk, wb.x, acc[i][4]);
                        acc[i][5] = fmaf(xk, wb.y, acc[i][5]);
                        acc[i][6] = fmaf(xk, wb.z, acc[i][6]);
                        acc[i][7] = fmaf(xk, wb.w, acc[i][7]);
                    }
                }
            }
        }
    }

#pragma unroll
    for (int i = 0; i < 4; ++i) {
        int row = base + r0 + i;
        if (row < n) {
            *(float4*)(Y + (size_t)row * C + c0) =
                make_float4(acc[i][0], acc[i][1], acc[i][2], acc[i][3]);
            if constexpr (CPT == 8)
                *(float4*)(Y + (size_t)row * C + c0 + 4) =
                    make_float4(acc[i][4], acc[i][5], acc[i][6], acc[i][7]);
        }
    }
}

// ---------------- fused gather(64ch) + relu + GEMM(64->CO)  (R8 config, int2 edges) ----
// Block = 64 nodes. Phase 1: 16 quarter-waves (16 lanes, float4 = 256B/row),
// 4 nodes each, unroll-4 edge loop -> Ys[64][64] XOR-swizzled in 16B blocks.
// Phase 2: 256 threads, rows {rg, rg+32} x CPT cols, W staged in LDS.

template <int CO>
__global__ __launch_bounds__(256) void k_gg(const float* __restrict__ HW,
                                            const int* __restrict__ off,
                                            const int2* __restrict__ ewn,
                                            const float* __restrict__ dis,
                                            const float* __restrict__ bias,
                                            const float* __restrict__ W,
                                            float* __restrict__ Yout, int n) {
    __shared__ float Ys[64 * 64];
    __shared__ float Ws[64 * CO];

    const int base = blockIdx.x * 64;

    // stage W (64 x CO)
    for (int v = threadIdx.x; v < 64 * CO / 4; v += 256)
        ((float4*)Ws)[v] = ((const float4*)W)[v];

    // phase 1: 16 quarter-waves x 4 nodes
    {
        const int qw = threadIdx.x >> 4;
        const int l = threadIdx.x & 15;
        const float4* HW4 = (const float4*)HW;
        const float4 bb = ((const float4*)bias)[l];
#pragma unroll 1
        for (int p = 0; p < 4; ++p) {
            int m = qw * 4 + p;
            int node = base + m;
            if (node < n) {
                float dd = dis[node];
                float4 hv = HW4[node * 16 + l];
                float4 A0, A1, A2, A3;
                A0.x = fmaf(dd * dd, hv.x, bb.x);
                A0.y = fmaf(dd * dd, hv.y, bb.y);
                A0.z = fmaf(dd * dd, hv.z, bb.z);
                A0.w = fmaf(dd * dd, hv.w, bb.w);
                A1 = make_float4(0.f, 0.f, 0.f, 0.f);
                A2 = A1; A3 = A1;
                int j = off[node], end = off[node + 1];
                for (; j + 3 < end; j += 4) {
                    int2 e0 = ewn[j], e1 = ewn[j + 1], e2 = ewn[j + 2], e3 = ewn[j + 3];
                    float w0 = __int_as_float(e0.y);
                    float w1 = __int_as_float(e1.y);
                    float w2 = __int_as_float(e2.y);
                    float w3 = __int_as_float(e3.y);
                    float4 v0 = HW4[e0.x * 16 + l];
                    float4 v1 = HW4[e1.x * 16 + l];
                    float4 v2 = HW4[e2.x * 16 + l];
                    float4 v3 = HW4[e3.x * 16 + l];
                    A0.x = fmaf(w0, v0.x, A0.x); A0.y = fmaf(w0, v0.y, A0.y);
                    A0.z = fmaf(w0, v0.z, A0.z); A0.w = fmaf(w0, v0.w, A0.w);
                    A1.x = fmaf(w1, v1.x, A1.x); A1.y = fmaf(w1, v1.y, A1.y);
                    A1.z = fmaf(w1, v1.z, A1.z); A1.w = fmaf(w1, v1.w, A1.w);
                    A2.x = fmaf(w2, v2.x, A2.x); A2.y = fmaf(w2, v2.y, A2.y);
                    A2.z = fmaf(w2, v2.z, A2.z); A2.w = fmaf(w2, v2.w, A2.w);
                    A3.x = fmaf(w3, v3.x, A3.x); A3.y = fmaf(w3, v3.y, A3.y);
                    A3.z = fmaf(w3, v3.z, A3.z); A3.w = fmaf(w3, v3.w, A3.w);
                }
                for (; j < end; ++j) {
                    int2 e0 = ewn[j];
                    float w0 = __int_as_float(e0.y);
                    float4 v0 = HW4[e0.x * 16 + l];
                    A0.x = fmaf(w0, v0.x, A0.x); A0.y = fmaf(w0, v0.y, A0.y);
                    A0.z = fmaf(w0, v0.z, A0.z); A0.w = fmaf(w0, v0.w, A0.w);
                }
                float4 o;
                o.x = fmaxf((A0.x + A1.x) + (A2.x + A3.x), 0.f);
                o.y = fmaxf((A0.y + A1.y) + (A2.y + A3.y), 0.f);
                o.z = fmaxf((A0.z + A1.z) + (A2.z + A3.z), 0.f);
                o.w = fmaxf((A0.w + A1.w) + (A2.w + A3.w), 0.f);
                *(float4*)&Ys[m * 64 + ((l ^ (m & 7)) << 2)] = o;   // swizzled 16B block
            }
        }
    }
    __syncthreads();

    // phase 2: Yout[64][CO] = Ys @ Ws ; thread tile = rows {rg, rg+32} x CPT
    constexpr int CPT = (CO == 32) ? 4 : 8;
    const int cg = threadIdx.x & 7;       // 8 col groups
    const int rg = threadIdx.x >> 3;      // 0..31
    const int c0 = cg * CPT;
    const int sw = rg & 7;                // row&7, same for rg and rg+32

    float acc[2][CPT];
#pragma unroll
    for (int i = 0; i < 2; ++i)
#pragma unroll
        for (int j = 0; j < CPT; ++j) acc[i][j] = 0.f;

#pragma unroll 1
    for (int kb = 0; kb < 16; ++kb) {
        const int k = kb * 4;
        float4 xv0 = *(const float4*)&Ys[rg * 64 + ((kb ^ sw) << 2)];
        float4 xv1 = *(const float4*)&Ys[(rg + 32) * 64 + ((kb ^ sw) << 2)];
#pragma unroll
        for (int kk = 0; kk < 4; ++kk) {
            float4 wa = *(const float4*)&Ws[(k + kk) * CO + c0];
            float4 wb;
            if constexpr (CPT == 8)
                wb = *(const float4*)&Ws[(k + kk) * CO + c0 + 4];
            float x0 = ((const float*)&xv0)[kk];
            float x1 = ((const float*)&xv1)[kk];
            acc[0][0] = fmaf(x0, wa.x, acc[0][0]); acc[1][0] = fmaf(x1, wa.x, acc[1][0]);
            acc[0][1] = fmaf(x0, wa.y, acc[0][1]); acc[1][1] = fmaf(x1, wa.y, acc[1][1]);
            acc[0][2] = fmaf(x0, wa.z, acc[0][2]); acc[1][2] = fmaf(x1, wa.z, acc[1][2]);
            acc[0][3] = fmaf(x0, wa.w, acc[0][3]); acc[1][3] = fmaf(x1, wa.w, acc[1][3]);
            if constexpr (CPT == 8) {
                acc[0][4] = fmaf(x0, wb.x, acc[0][4]); acc[1][4] = fmaf(x1, wb.x, acc[1][4]);
                acc[0][5] = fmaf(x0, wb.y, acc[0][5]); acc[1][5] = fmaf(x1, wb.y, acc[1][5]);
                acc[0][6] = fmaf(x0, wb.z, acc[0][6]); acc[1][6] = fmaf(x1, wb.z, acc[1][6]);
                acc[0][7] = fmaf(x0, wb.w, acc[0][7]); acc[1][7] = fmaf(x1, wb.w, acc[1][7]);
            }
        }
    }

#pragma unroll
    for (int i = 0; i < 2; ++i) {
        int row = base + rg + 32 * i;
        if (row < n) {
            *(float4*)(Yout + (size_t)row * CO + c0) =
                make_float4(acc[i][0], acc[i][1], acc[i][2], acc[i][3]);
            if constexpr (CPT == 8)
                *(float4*)(Yout + (size_t)row * CO + c0 + 4) =
                    make_float4(acc[i][4], acc[i][5], acc[i][6], acc[i][7]);
        }
    }
}

// ---------------- final CSR gather (32ch), quarter-wave float2, int2 edges ----------------

__global__ __launch_bounds__(TPB) void k_gather32(const float* __restrict__ HW,
                                                  const int* __restrict__ off,
                                                  const int2* __restrict__ ewn,
                                                  const float* __restrict__ dis,
                                                  const float* __restrict__ b,
                                                  float* __restrict__ Y, int n) {
    int node = (blockIdx.x * blockDim.x + threadIdx.x) >> 4;
    int l = threadIdx.x & 15;
    if (node >= n) return;
    const float2* HW2 = (const float2*)HW;
    float dd = dis[node];
    float2 hv = HW2[node * 16 + l];
    float2 bb = ((const float2*)b)[l];
    float a0x = fmaf(dd * dd, hv.x, bb.x);
    float a0y = fmaf(dd * dd, hv.y, bb.y);
    float a1x = 0.f, a1y = 0.f, a2x = 0.f, a2y = 0.f, a3x = 0.f, a3y = 0.f;
    int j = off[node], end = off[node + 1];
    for (; j + 3 < end; j += 4) {
        int2 e0 = ewn[j], e1 = ewn[j + 1], e2 = ewn[j + 2], e3 = ewn[j + 3];
        float w0 = __int_as_float(e0.y);
        float w1 = __int_as_float(e1.y);
        float w2 = __int_as_float(e2.y);
        float w3 = __int_as_float(e3.y);
        float2 v0 = HW2[e0.x * 16 + l];
        float2 v1 = HW2[e1.x * 16 + l];
        float2 v2 = HW2[e2.x * 16 + l];
        float2 v3 = HW2[e3.x * 16 + l];
        a0x = fmaf(w0, v0.x, a0x); a0y = fmaf(w0, v0.y, a0y);
        a1x = fmaf(w1, v1.x, a1x); a1y = fmaf(w1, v1.y, a1y);
        a2x = fmaf(w2, v2.x, a2x); a2y = fmaf(w2, v2.y, a2y);
        a3x = fmaf(w3, v3.x, a3x); a3y = fmaf(w3, v3.y, a3y);
    }
    for (; j < end; ++j) {
        int2 e0 = ewn[j];
        float w0 = __int_as_float(e0.y);
        float2 v0 = HW2[e0.x * 16 + l];
        a0x = fmaf(w0, v0.x, a0x); a0y = fmaf(w0, v0.y, a0y);
    }
    float2 o;
    o.x = (a0x + a1x) + (a2x + a3x);
    o.y = (a0y + a1y) + (a2y + a3y);
    ((float2*)Y)[node * 16 + l] = o;
}

// ---------------- launch ----------------

extern "C" void kernel_launch(void* const* d_in, const int* in_sizes, int n_in,
                              void* d_out, int out_size, void* d_ws, size_t ws_size,
                              hipStream_t stream) {
    const float* x  = (const float*)d_in[0];
    const int*   ei = (const int*)d_in[1];
    const float* ew = (const float*)d_in[2];
    const float* W1 = (const float*)d_in[3];
    const float* b1 = (const float*)d_in[4];
    const float* W2 = (const float*)d_in[5];
    const float* b2 = (const float*)d_in[6];
    const float* W3 = (const float*)d_in[7];
    const float* b3 = (const float*)d_in[8];
    float* out = (float*)d_out;

    const int IN_C = 128, HID_C = 64;
    const int N = in_sizes[0] / IN_C;   // 100000 (< 2^17, required by packing)
    const int E = in_sizes[2];          // 1600000

    const int* src = ei;       // edge_index[0] = row (gather source)
    const int* dst = ei + E;   // edge_index[1] = col (destination)

    const int NB   = (N + BKT - 1) / BKT;        // 196 buckets (<=256 required)
    const int NBLK = (E + CH - 1) / CH;          // 196 chunk-blocks
    const int LM   = NB * NBLK;                  // count-matrix size

    // ---- workspace layout ----
    char* w = (char*)d_ws;
    float* dis   = (float*)w;                 w += sizeof(float) * N;
    int*   off   = (int*)w;                   w += sizeof(int) * (N + 1);
    int*   bkst  = (int*)w;                   w += sizeof(int) * (NB + 1);
    int*   bsum  = (int*)w;                   w += sizeof(int) * 64;
    w = (char*)(((size_t)w + 15) & ~(size_t)15);
    int2*  ewn   = (int2*)w;                  w += sizeof(int2) * E;
    // transient region: [M | barr] overlapped later by [A | B]
    char* w2 = (char*)(((size_t)w + 15) & ~(size_t)15);
    int*  M    = (int*)w2;
    int2* barr = (int2*)(((size_t)(M + LM) + 15) & ~(size_t)15);   // E int2
    float* A   = (float*)w2;                                       // N*64 (also A3: N*32)
    float* B   = A + (size_t)N * HID_C;                            // N*64

    const int nScanM = (LM + SC_TPB * SC_ITEMS - 1) / (SC_TPB * SC_ITEMS);  // 19 <= 64

    // ---- build CSR + normalization (no global atomics) ----
    k_bucket_count<<<NBLK, 256, 0, stream>>>(dst, M, E, NB, NBLK);
    k_scan_blocks<<<nScanM, SC_TPB, 0, stream>>>(M, bsum, LM);
    k_scan_final<<<nScanM, SC_TPB, 0, stream>>>(M, bsum, M, bkst, NBLK, LM, E,
                                                off + N, bkst + NB);
    k_bucket_scatter<<<NBLK, 256, 0, stream>>>(src, dst, ew, M, barr, E, NB, NBLK);
    k_csr_build<<<NB, 256, 0, stream>>>(barr, bkst, dis, off, ewn, N);
    k_finw<<<(E + 255) / 256, 256, 0, stream>>>(ewn, dis, E);

    const int nT128 = (N + 127) / 128;
    const int nT64  = (N + 63) / 64;
    const int gQ    = (N * 16 + TPB - 1) / TPB;   // quarter-wave per node

    // ---- layer 1 GEMM: A = x @ W1 ----
    k_gemm<128, 64, false><<<nT128, 256, 0, stream>>>(x, W1, A, N);
    // ---- fused: B = relu(agg(A) + b1) @ W2 ----
    k_gg<64><<<nT64, 256, 0, stream>>>(A, off, ewn, dis, b1, W2, B, N);
    // ---- fused: A3 = relu(agg(B) + b2) @ W3  (A3 reuses A region, N*32) ----
    k_gg<32><<<nT64, 256, 0, stream>>>(B, off, ewn, dis, b2, W3, A, N);
    // ---- final: out = agg(A3) + b3 ----
    k_gather32<<<gQ, TPB, 0, stream>>>(A, off, ewn, dis, b3, out, N);
}

// Round 13
// 300.235 us; speedup vs baseline: 1.3644x; 1.2206x over previous
//
#include <hip/hip_runtime.h>
#include <math.h>

#define TPB 256
#define SC_TPB 256
#define SC_ITEMS 8   // 2048 elements per scan block
#define CH 8192      // edges per bucket-pass block
#define BKT 512      // nodes per bucket (bucket = dst >> 9)

// ---------------- bf16 helpers (storage only; all math fp32) ----------------

__device__ __forceinline__ unsigned short f2bf(float f) {   // RNE
    unsigned int u = __float_as_uint(f);
    unsigned int r = u + 0x7FFFu + ((u >> 16) & 1u);
    return (unsigned short)(r >> 16);
}
__device__ __forceinline__ float bflo(unsigned int u) { return __uint_as_float(u << 16); }
__device__ __forceinline__ float bfhi(unsigned int u) { return __uint_as_float(u & 0xFFFF0000u); }

// ---------------- multi-block exclusive scan (2 kernels) ----------------

__global__ __launch_bounds__(SC_TPB) void k_scan_blocks(const int* __restrict__ cnt,
                                                        int* __restrict__ bsum, int n) {
    __shared__ int red[SC_TPB / 64];
    int base = blockIdx.x * SC_TPB * SC_ITEMS;
    int s = 0;
    for (int it = 0; it < SC_ITEMS; ++it) {
        int i = base + it * SC_TPB + threadIdx.x;
        if (i < n) s += cnt[i];
    }
    for (int d = 1; d < 64; d <<= 1) s += __shfl_xor(s, d);
    if ((threadIdx.x & 63) == 0) red[threadIdx.x >> 6] = s;
    __syncthreads();
    if (threadIdx.x == 0) {
        int t = 0;
        for (int w = 0; w < SC_TPB / 64; ++w) t += red[w];
        bsum[blockIdx.x] = t;
    }
}

// final scan pass; computes its own block-prefix from raw bsum (<=64 entries);
// emits bkst[b] = scanned[b*nblk]; block 0 writes off[N]=E, bkst[NB]=E.
__global__ __launch_bounds__(SC_TPB) void k_scan_final(const int* __restrict__ cnt,
                                                       const int* __restrict__ bsum,
                                                       int* __restrict__ off,
                                                       int* __restrict__ bkst, int nblk,
                                                       int n, int total,
                                                       int* __restrict__ off_n,
                                                       int* __restrict__ bkst_n) {
    __shared__ int wsum[SC_TPB / 64];
    int bpref = 0;
    for (int i = 0; i < (int)blockIdx.x; ++i) bpref += bsum[i];  // uniform, <=64 iters
    int base = blockIdx.x * SC_TPB * SC_ITEMS;
    int tbase = base + threadIdx.x * SC_ITEMS;
    int loc[SC_ITEMS];
    int s = 0;
    for (int it = 0; it < SC_ITEMS; ++it) {
        int i = tbase + it;
        int v = (i < n) ? cnt[i] : 0;
        loc[it] = s;
        s += v;
    }
    int l = threadIdx.x & 63, wv = threadIdx.x >> 6;
    int inc = s;
    for (int d = 1; d < 64; d <<= 1) {
        int t = __shfl_up(inc, d);
        if (l >= d) inc += t;
    }
    int thr_ex = inc - s;
    if (l == 63) wsum[wv] = inc;
    __syncthreads();
    int woff = 0;
    for (int w = 0; w < wv; ++w) woff += wsum[w];
    int pref = bpref + woff + thr_ex;
    for (int it = 0; it < SC_ITEMS; ++it) {
        int i = tbase + it;
        if (i < n) {
            int val = pref + loc[it];
            off[i] = val;
            if (i % nblk == 0) bkst[i / nblk] = val;
        }
    }
    if (blockIdx.x == 0 && threadIdx.x == 0) { *off_n = total; *bkst_n = total; }
}

// ---------------- bucket pass 1: per-(bucket, block) counts, LDS histogram ----------------

__global__ __launch_bounds__(256) void k_bucket_count(const int* __restrict__ dst,
                                                      int* __restrict__ M,
                                                      int e, int nb, int nblk) {
    __shared__ int h[256];  // nb <= 256 (N <= 131072)
    for (int i = threadIdx.x; i < nb; i += 256) h[i] = 0;
    __syncthreads();
    int base = blockIdx.x * CH;
    int lim = min(base + CH, e);
    for (int i = base + threadIdx.x; i < lim; i += 256)
        atomicAdd(&h[dst[i] >> 9], 1);
    __syncthreads();
    for (int b = threadIdx.x; b < nb; b += 256)
        M[b * nblk + blockIdx.x] = h[b];
}

// ---------------- bucket pass 2: scatter packed edges into bucket regions ----------------
// packed: src (17 bits, N<=131072) | dst_local (9 bits) << 17

__global__ __launch_bounds__(256) void k_bucket_scatter(const int* __restrict__ src,
                                                        const int* __restrict__ dst,
                                                        const float* __restrict__ w,
                                                        const int* __restrict__ Ms,
                                                        int2* __restrict__ barr,
                                                        int e, int nb, int nblk) {
    __shared__ int cur[256];
    for (int i = threadIdx.x; i < nb; i += 256) cur[i] = Ms[i * nblk + blockIdx.x];
    __syncthreads();
    int base = blockIdx.x * CH;
    int lim = min(base + CH, e);
    for (int i = base + threadIdx.x; i < lim; i += 256) {
        int d = dst[i];
        int p = atomicAdd(&cur[d >> 9], 1);  // LDS cursor
        barr[p] = make_int2(src[i] | ((d & 511) << 17), __float_as_int(w[i]));
    }
}

// ---------------- bucket pass 3: per-bucket CSR build + degree/dis ----------------
// Emits ewn[p] = {src, w * dis[dst]} (int2); dis[src] folded in by k_finw.

__global__ __launch_bounds__(256) void k_csr_build(const int2* __restrict__ barr,
                                                   const int* __restrict__ bucketStart,
                                                   float* __restrict__ dis,
                                                   int* __restrict__ off,
                                                   int2* __restrict__ ewn, int n) {
    int b = blockIdx.x;
    int nbase = b << 9;
    int ebeg = bucketStart[b], eend = bucketStart[b + 1];
    __shared__ int cnt[BKT];
    __shared__ float wsum[BKT];
    __shared__ float disL[BKT];
    __shared__ int scn[BKT];
    __shared__ int wtot[4];

    for (int i = threadIdx.x; i < BKT; i += 256) { cnt[i] = 0; wsum[i] = 0.f; }
    __syncthreads();
    for (int j = ebeg + threadIdx.x; j < eend; j += 256) {
        int2 ed = barr[j];
        int dl = ed.x >> 17;
        atomicAdd(&cnt[dl], 1);
        atomicAdd(&wsum[dl], __int_as_float(ed.y));
    }
    __syncthreads();

    int t = threadIdx.x;
    int a0 = cnt[2 * t], a1 = cnt[2 * t + 1];
    int s = a0 + a1;
    int l = t & 63, wv = t >> 6;
    int inc = s;
    for (int d = 1; d < 64; d <<= 1) {
        int u = __shfl_up(inc, d);
        if (l >= d) inc += u;
    }
    if (l == 63) wtot[wv] = inc;
    for (int i = threadIdx.x; i < BKT; i += 256) {
        int node = nbase + i;
        if (node < n) {
            float dv = rsqrtf(1.0f + wsum[i]);  // deg = 1 (self-loop) + sum(w) > 0
            disL[i] = dv;
            dis[node] = dv;
        }
    }
    __syncthreads();
    int woff = 0;
    for (int k = 0; k < wv; ++k) woff += wtot[k];
    int ex = woff + inc - s;
    scn[2 * t] = ex;
    scn[2 * t + 1] = ex + a0;
    __syncthreads();
    for (int i = threadIdx.x; i < BKT; i += 256) {
        int node = nbase + i;
        if (node < n) off[node] = ebeg + scn[i];
    }
    __syncthreads();
    for (int j = ebeg + threadIdx.x; j < eend; j += 256) {
        int2 ed = barr[j];
        int dl = ed.x >> 17;
        int p = ebeg + atomicAdd(&scn[dl], 1);
        ewn[p] = make_int2(ed.x & 0x1FFFF,
                           __float_as_int(__int_as_float(ed.y) * disL[dl]));
    }
}

// fold dis[src] into the edge weight: ewn[i].y = w * dis[dst] * dis[src]
__global__ void k_finw(int2* __restrict__ ewn, const float* __restrict__ dis, int e) {
    int i = blockIdx.x * blockDim.x + threadIdx.x;
    if (i < e) {
        int2 v = ewn[i];
        ewn[i].y = __float_as_int(__int_as_float(v.y) * dis[v.x]);
    }
}

// ---------------- dense GEMM  Ybf16[n,C] = X[n,K] @ W[K,C]  (layer 1 only) ----------------

template <int K, int C>
__global__ __launch_bounds__(256) void k_gemm(const float* __restrict__ X,
                                              const float* __restrict__ W,
                                              unsigned short* __restrict__ Y, int n) {
    constexpr int CPT = 8;
    constexpr int CG = C / CPT;            // 8
    constexpr int RG = 256 / CG;           // 32
    constexpr int M = RG * 4;              // 128 rows per block
    constexpr int KC = (K > 64) ? 64 : K;  // K chunk
    constexpr int NKB = KC / 4;            // 16B k-blocks per chunk

    __shared__ float Ws[KC * C];
    __shared__ float Xs[M * KC];

    const int cg = threadIdx.x & (CG - 1);
    const int rg = threadIdx.x / CG;
    const int c0 = cg * CPT;
    const int r0 = rg * 4;
    const int base = blockIdx.x * M;

    float acc[4][CPT];
#pragma unroll
    for (int i = 0; i < 4; ++i)
#pragma unroll
        for (int j = 0; j < CPT; ++j) acc[i][j] = 0.f;

    for (int kc = 0; kc < K; kc += KC) {
        if (kc) __syncthreads();
        const float4* Wg4 = (const float4*)(W + (size_t)kc * C);
        for (int v = threadIdx.x; v < KC * C / 4; v += 256)
            ((float4*)Ws)[v] = Wg4[v];
        for (int v = threadIdx.x; v < M * NKB; v += 256) {
            int m = v / NKB, kb = v % NKB;
            int row = base + m;
            float4 val = make_float4(0.f, 0.f, 0.f, 0.f);
            if (row < n) val = *(const float4*)(X + (size_t)row * K + kc + kb * 4);
            *(float4*)&Xs[m * KC + ((kb ^ (m & 3)) << 2)] = val;
        }
        __syncthreads();

#pragma unroll 1
        for (int kb = 0; kb < NKB; ++kb) {
            const int k = kb * 4;
            float4 xv[4];
#pragma unroll
            for (int i = 0; i < 4; ++i)
                xv[i] = *(const float4*)&Xs[(r0 + i) * KC + ((kb ^ i) << 2)];
#pragma unroll
            for (int kk = 0; kk < 4; ++kk) {
                float4 wa = *(const float4*)&Ws[(k + kk) * C + c0];
                float4 wb = *(const float4*)&Ws[(k + kk) * C + c0 + 4];
#pragma unroll
                for (int i = 0; i < 4; ++i) {
                    float xk = ((const float*)&xv[i])[kk];
                    acc[i][0] = fmaf(xk, wa.x, acc[i][0]);
                    acc[i][1] = fmaf(xk, wa.y, acc[i][1]);
                    acc[i][2] = fmaf(xk, wa.z, acc[i][2]);
                    acc[i][3] = fmaf(xk, wa.w, acc[i][3]);
                    acc[i][4] = fmaf(xk, wb.x, acc[i][4]);
                    acc[i][5] = fmaf(xk, wb.y, acc[i][5]);
                    acc[i][6] = fmaf(xk, wb.z, acc[i][6]);
                    acc[i][7] = fmaf(xk, wb.w, acc[i][7]);
                }
            }
        }
    }

#pragma unroll
    for (int i = 0; i < 4; ++i) {
        int row = base + r0 + i;
        if (row < n) {
            uint4 o;
            o.x = (unsigned int)f2bf(acc[i][0]) | ((unsigned int)f2bf(acc[i][1]) << 16);
            o.y = (unsigned int)f2bf(acc[i][2]) | ((unsigned int)f2bf(acc[i][3]) << 16);
            o.z = (unsigned int)f2bf(acc[i][4]) | ((unsigned int)f2bf(acc[i][5]) << 16);
            o.w = (unsigned int)f2bf(acc[i][6]) | ((unsigned int)f2bf(acc[i][7]) << 16);
            *(uint4*)(Y + (size_t)row * C + c0) = o;
        }
    }
}

// ---------------- fused gather(64ch bf16) + relu + GEMM(64->CO) -> bf16 ----
// Block = 64 nodes. Phase 1: 16 quarter-waves (16 lanes, uint2 = 4 bf16 = 8B/lane,
// 128B/row), 4 nodes each, unroll-4 edge loop -> Ys[64][64] fp32 XOR-swizzled.
// Phase 2: 256 threads, rows {rg, rg+32} x CPT cols, W (fp32) staged in LDS.

template <int CO>
__global__ __launch_bounds__(256) void k_gg(const unsigned short* __restrict__ HW,
                                            const int* __restrict__ off,
                                            const int2* __restrict__ ewn,
                                            const float* __restrict__ dis,
                                            const float* __restrict__ bias,
                                            const float* __restrict__ W,
                                            unsigned short* __restrict__ Yout, int n) {
    __shared__ float Ys[64 * 64];
    __shared__ float Ws[64 * CO];

    const int base = blockIdx.x * 64;

    // stage W (64 x CO)
    for (int v = threadIdx.x; v < 64 * CO / 4; v += 256)
        ((float4*)Ws)[v] = ((const float4*)W)[v];

    // phase 1: 16 quarter-waves x 4 nodes
    {
        const int qw = threadIdx.x >> 4;
        const int l = threadIdx.x & 15;
        const uint2* HW8 = (const uint2*)HW;   // 4 bf16 per uint2
        const float4 bb = ((const float4*)bias)[l];
#pragma unroll 1
        for (int p = 0; p < 4; ++p) {
            int m = qw * 4 + p;
            int node = base + m;
            if (node < n) {
                float dd = dis[node];
                uint2 hu = HW8[node * 16 + l];
                float4 A0, A1, A2, A3;
                A0.x = fmaf(dd * dd, bflo(hu.x), bb.x);
                A0.y = fmaf(dd * dd, bfhi(hu.x), bb.y);
                A0.z = fmaf(dd * dd, bflo(hu.y), bb.z);
                A0.w = fmaf(dd * dd, bfhi(hu.y), bb.w);
                A1 = make_float4(0.f, 0.f, 0.f, 0.f);
                A2 = A1; A3 = A1;
                int j = off[node], end = off[node + 1];
                for (; j + 3 < end; j += 4) {
                    int2 e0 = ewn[j], e1 = ewn[j + 1], e2 = ewn[j + 2], e3 = ewn[j + 3];
                    float w0 = __int_as_float(e0.y);
                    float w1 = __int_as_float(e1.y);
                    float w2 = __int_as_float(e2.y);
                    float w3 = __int_as_float(e3.y);
                    uint2 u0 = HW8[e0.x * 16 + l];
                    uint2 u1 = HW8[e1.x * 16 + l];
                    uint2 u2 = HW8[e2.x * 16 + l];
                    uint2 u3 = HW8[e3.x * 16 + l];
                    A0.x = fmaf(w0, bflo(u0.x), A0.x); A0.y = fmaf(w0, bfhi(u0.x), A0.y);
                    A0.z = fmaf(w0, bflo(u0.y), A0.z); A0.w = fmaf(w0, bfhi(u0.y), A0.w);
                    A1.x = fmaf(w1, bflo(u1.x), A1.x); A1.y = fmaf(w1, bfhi(u1.x), A1.y);
                    A1.z = fmaf(w1, bflo(u1.y), A1.z); A1.w = fmaf(w1, bfhi(u1.y), A1.w);
                    A2.x = fmaf(w2, bflo(u2.x), A2.x); A2.y = fmaf(w2, bfhi(u2.x), A2.y);
                    A2.z = fmaf(w2, bflo(u2.y), A2.z); A2.w = fmaf(w2, bfhi(u2.y), A2.w);
                    A3.x = fmaf(w3, bflo(u3.x), A3.x); A3.y = fmaf(w3, bfhi(u3.x), A3.y);
                    A3.z = fmaf(w3, bflo(u3.y), A3.z); A3.w = fmaf(w3, bfhi(u3.y), A3.w);
                }
                for (; j < end; ++j) {
                    int2 e0 = ewn[j];
                    float w0 = __int_as_float(e0.y);
                    uint2 u0 = HW8[e0.x * 16 + l];
                    A0.x = fmaf(w0, bflo(u0.x), A0.x); A0.y = fmaf(w0, bfhi(u0.x), A0.y);
                    A0.z = fmaf(w0, bflo(u0.y), A0.z); A0.w = fmaf(w0, bfhi(u0.y), A0.w);
                }
                float4 o;
                o.x = fmaxf((A0.x + A1.x) + (A2.x + A3.x), 0.f);
                o.y = fmaxf((A0.y + A1.y) + (A2.y + A3.y), 0.f);
                o.z = fmaxf((A0.z + A1.z) + (A2.z + A3.z), 0.f);
                o.w = fmaxf((A0.w + A1.w) + (A2.w + A3.w), 0.f);
                *(float4*)&Ys[m * 64 + ((l ^ (m & 7)) << 2)] = o;   // swizzled 16B block
            }
        }
    }
    __syncthreads();

    // phase 2: Yout[64][CO] (bf16) = Ys @ Ws ; thread tile = rows {rg, rg+32} x CPT
    constexpr int CPT = (CO == 32) ? 4 : 8;
    const int cg = threadIdx.x & 7;       // 8 col groups
    const int rg = threadIdx.x >> 3;      // 0..31
    const int c0 = cg * CPT;
    const int sw = rg & 7;                // row&7, same for rg and rg+32

    float acc[2][CPT];
#pragma unroll
    for (int i = 0; i < 2; ++i)
#pragma unroll
        for (int j = 0; j < CPT; ++j) acc[i][j] = 0.f;

#pragma unroll 1
    for (int kb = 0; kb < 16; ++kb) {
        const int k = kb * 4;
        float4 xv0 = *(const float4*)&Ys[rg * 64 + ((kb ^ sw) << 2)];
        float4 xv1 = *(const float4*)&Ys[(rg + 32) * 64 + ((kb ^ sw) << 2)];
#pragma unroll
        for (int kk = 0; kk < 4; ++kk) {
            float4 wa = *(const float4*)&Ws[(k + kk) * CO + c0];
            float4 wb;
            if constexpr (CPT == 8)
                wb = *(const float4*)&Ws[(k + kk) * CO + c0 + 4];
            float x0 = ((const float*)&xv0)[kk];
            float x1 = ((const float*)&xv1)[kk];
            acc[0][0] = fmaf(x0, wa.x, acc[0][0]); acc[1][0] = fmaf(x1, wa.x, acc[1][0]);
            acc[0][1] = fmaf(x0, wa.y, acc[0][1]); acc[1][1] = fmaf(x1, wa.y, acc[1][1]);
            acc[0][2] = fmaf(x0, wa.z, acc[0][2]); acc[1][2] = fmaf(x1, wa.z, acc[1][2]);
            acc[0][3] = fmaf(x0, wa.w, acc[0][3]); acc[1][3] = fmaf(x1, wa.w, acc[1][3]);
            if constexpr (CPT == 8) {
                acc[0][4] = fmaf(x0, wb.x, acc[0][4]); acc[1][4] = fmaf(x1, wb.x, acc[1][4]);
                acc[0][5] = fmaf(x0, wb.y, acc[0][5]); acc[1][5] = fmaf(x1, wb.y, acc[1][5]);
                acc[0][6] = fmaf(x0, wb.z, acc[0][6]); acc[1][6] = fmaf(x1, wb.z, acc[1][6]);
                acc[0][7] = fmaf(x0, wb.w, acc[0][7]); acc[1][7] = fmaf(x1, wb.w, acc[1][7]);
            }
        }
    }

#pragma unroll
    for (int i = 0; i < 2; ++i) {
        int row = base + rg + 32 * i;
        if (row < n) {
            if constexpr (CPT == 8) {
                uint4 o;
                o.x = (unsigned int)f2bf(acc[i][0]) | ((unsigned int)f2bf(acc[i][1]) << 16);
                o.y = (unsigned int)f2bf(acc[i][2]) | ((unsigned int)f2bf(acc[i][3]) << 16);
                o.z = (unsigned int)f2bf(acc[i][4]) | ((unsigned int)f2bf(acc[i][5]) << 16);
                o.w = (unsigned int)f2bf(acc[i][6]) | ((unsigned int)f2bf(acc[i][7]) << 16);
                *(uint4*)(Yout + (size_t)row * CO + c0) = o;
            } else {
                uint2 o;
                o.x = (unsigned int)f2bf(acc[i][0]) | ((unsigned int)f2bf(acc[i][1]) << 16);
                o.y = (unsigned int)f2bf(acc[i][2]) | ((unsigned int)f2bf(acc[i][3]) << 16);
                *(uint2*)(Yout + (size_t)row * CO + c0) = o;
            }
        }
    }
}

// ---------------- final CSR gather (32ch bf16 in, fp32 out), quarter-wave ----------------

__global__ __launch_bounds__(TPB) void k_gather32(const unsigned short* __restrict__ HW,
                                                  const int* __restrict__ off,
                                                  const int2* __restrict__ ewn,
                                                  const float* __restrict__ dis,
                                                  const float* __restrict__ b,
                                                  float* __restrict__ Y, int n) {
    int node = (blockIdx.x * blockDim.x + threadIdx.x) >> 4;
    int l = threadIdx.x & 15;
    if (node >= n) return;
    const unsigned int* HWu = (const unsigned int*)HW;  // 2 bf16 per uint
    float dd = dis[node];
    unsigned int hu = HWu[node * 16 + l];
    float2 bb = ((const float2*)b)[l];
    float a0x = fmaf(dd * dd, bflo(hu), bb.x);
    float a0y = fmaf(dd * dd, bfhi(hu), bb.y);
    float a1x = 0.f, a1y = 0.f, a2x = 0.f, a2y = 0.f, a3x = 0.f, a3y = 0.f;
    int j = off[node], end = off[node + 1];
    for (; j + 3 < end; j += 4) {
        int2 e0 = ewn[j], e1 = ewn[j + 1], e2 = ewn[j + 2], e3 = ewn[j + 3];
        float w0 = __int_as_float(e0.y);
        float w1 = __int_as_float(e1.y);
        float w2 = __int_as_float(e2.y);
        float w3 = __int_as_float(e3.y);
        unsigned int u0 = HWu[e0.x * 16 + l];
        unsigned int u1 = HWu[e1.x * 16 + l];
        unsigned int u2 = HWu[e2.x * 16 + l];
        unsigned int u3 = HWu[e3.x * 16 + l];
        a0x = fmaf(w0, bflo(u0), a0x); a0y = fmaf(w0, bfhi(u0), a0y);
        a1x = fmaf(w1, bflo(u1), a1x); a1y = fmaf(w1, bfhi(u1), a1y);
        a2x = fmaf(w2, bflo(u2), a2x); a2y = fmaf(w2, bfhi(u2), a2y);
        a3x = fmaf(w3, bflo(u3), a3x); a3y = fmaf(w3, bfhi(u3), a3y);
    }
    for (; j < end; ++j) {
        int2 e0 = ewn[j];
        float w0 = __int_as_float(e0.y);
        unsigned int u0 = HWu[e0.x * 16 + l];
        a0x = fmaf(w0, bflo(u0), a0x); a0y = fmaf(w0, bfhi(u0), a0y);
    }
    float2 o;
    o.x = (a0x + a1x) + (a2x + a3x);
    o.y = (a0y + a1y) + (a2y + a3y);
    ((float2*)Y)[node * 16 + l] = o;
}

// ---------------- launch ----------------

extern "C" void kernel_launch(void* const* d_in, const int* in_sizes, int n_in,
                              void* d_out, int out_size, void* d_ws, size_t ws_size,
                              hipStream_t stream) {
    const float* x  = (const float*)d_in[0];
    const int*   ei = (const int*)d_in[1];
    const float* ew = (const float*)d_in[2];
    const float* W1 = (const float*)d_in[3];
    const float* b1 = (const float*)d_in[4];
    const float* W2 = (const float*)d_in[5];
    const float* b2 = (const float*)d_in[6];
    const float* W3 = (const float*)d_in[7];
    const float* b3 = (const float*)d_in[8];
    float* out = (float*)d_out;

    const int IN_C = 128, HID_C = 64;
    const int N = in_sizes[0] / IN_C;   // 100000 (< 2^17, required by packing)
    const int E = in_sizes[2];          // 1600000

    const int* src = ei;       // edge_index[0] = row (gather source)
    const int* dst = ei + E;   // edge_index[1] = col (destination)

    const int NB   = (N + BKT - 1) / BKT;        // 196 buckets (<=256 required)
    const int NBLK = (E + CH - 1) / CH;          // 196 chunk-blocks
    const int LM   = NB * NBLK;                  // count-matrix size

    // ---- workspace layout ----
    char* w = (char*)d_ws;
    float* dis   = (float*)w;                 w += sizeof(float) * N;
    int*   off   = (int*)w;                   w += sizeof(int) * (N + 1);
    int*   bkst  = (int*)w;                   w += sizeof(int) * (NB + 1);
    int*   bsum  = (int*)w;                   w += sizeof(int) * 64;
    w = (char*)(((size_t)w + 15) & ~(size_t)15);
    int2*  ewn   = (int2*)w;                  w += sizeof(int2) * E;
    // transient region: [M | barr] overlapped later by [A | B] (bf16 tables)
    char* w2 = (char*)(((size_t)w + 15) & ~(size_t)15);
    int*  M    = (int*)w2;
    int2* barr = (int2*)(((size_t)(M + LM) + 15) & ~(size_t)15);   // E int2
    unsigned short* A = (unsigned short*)w2;                        // N*64 bf16 (also A3: N*32)
    unsigned short* B = A + (size_t)N * HID_C;                      // N*64 bf16

    const int nScanM = (LM + SC_TPB * SC_ITEMS - 1) / (SC_TPB * SC_ITEMS);  // 19 <= 64

    // ---- build CSR + normalization (no global atomics) ----
    k_bucket_count<<<NBLK, 256, 0, stream>>>(dst, M, E, NB, NBLK);
    k_scan_blocks<<<nScanM, SC_TPB, 0, stream>>>(M, bsum, LM);
    k_scan_final<<<nScanM, SC_TPB, 0, stream>>>(M, bsum, M, bkst, NBLK, LM, E,
                                                off + N, bkst + NB);
    k_bucket_scatter<<<NBLK, 256, 0, stream>>>(src, dst, ew, M, barr, E, NB, NBLK);
    k_csr_build<<<NB, 256, 0, stream>>>(barr, bkst, dis, off, ewn, N);
    k_finw<<<(E + 255) / 256, 256, 0, stream>>>(ewn, dis, E);

    const int nT128 = (N + 127) / 128;
    const int nT64  = (N + 63) / 64;
    const int gQ    = (N * 16 + TPB - 1) / TPB;   // quarter-wave per node

    // ---- layer 1 GEMM: A = bf16(x @ W1) ----
    k_gemm<128, 64><<<nT128, 256, 0, stream>>>(x, W1, A, N);
    // ---- fused: B = bf16( relu(agg(A) + b1) @ W2 ) ----
    k_gg<64><<<nT64, 256, 0, stream>>>(A, off, ewn, dis, b1, W2, B, N);
    // ---- fused: A3 = bf16( relu(agg(B) + b2) @ W3 )  (A3 reuses A region, N*32) ----
    k_gg<32><<<nT64, 256, 0, stream>>>(B, off, ewn, dis, b2, W3, A, N);
    // ---- final: out = agg(A3) + b3  (fp32) ----
    k_gather32<<<gQ, TPB, 0, stream>>>(A, off, ewn, dis, b3, out, N);
}

// Round 14
// 291.384 us; speedup vs baseline: 1.4059x; 1.0304x over previous
//
#include <hip/hip_runtime.h>
#include <math.h>

#define TPB 256
#define SC_TPB 256
#define SC_ITEMS 8   // 2048 elements per scan block
#define CH 8192      // edges per bucket-pass block
#define BKT 512      // nodes per bucket (bucket = dst >> 9)

// ---------------- bf16 helpers (storage only; all math fp32) ----------------

__device__ __forceinline__ unsigned short f2bf(float f) {   // RNE
    unsigned int u = __float_as_uint(f);
    unsigned int r = u + 0x7FFFu + ((u >> 16) & 1u);
    return (unsigned short)(r >> 16);
}
__device__ __forceinline__ float bflo(unsigned int u) { return __uint_as_float(u << 16); }
__device__ __forceinline__ float bfhi(unsigned int u) { return __uint_as_float(u & 0xFFFF0000u); }

// ---------------- multi-block exclusive scan (2 kernels) ----------------

__global__ __launch_bounds__(SC_TPB) void k_scan_blocks(const int* __restrict__ cnt,
                                                        int* __restrict__ bsum, int n) {
    __shared__ int red[SC_TPB / 64];
    int base = blockIdx.x * SC_TPB * SC_ITEMS;
    int s = 0;
    for (int it = 0; it < SC_ITEMS; ++it) {
        int i = base + it * SC_TPB + threadIdx.x;
        if (i < n) s += cnt[i];
    }
    for (int d = 1; d < 64; d <<= 1) s += __shfl_xor(s, d);
    if ((threadIdx.x & 63) == 0) red[threadIdx.x >> 6] = s;
    __syncthreads();
    if (threadIdx.x == 0) {
        int t = 0;
        for (int w = 0; w < SC_TPB / 64; ++w) t += red[w];
        bsum[blockIdx.x] = t;
    }
}

// final scan pass; computes its own block-prefix from raw bsum (<=64 entries);
// emits bkst[b] = scanned[b*nblk]; block 0 writes off[N]=E, bkst[NB]=E.
__global__ __launch_bounds__(SC_TPB) void k_scan_final(const int* __restrict__ cnt,
                                                       const int* __restrict__ bsum,
                                                       int* __restrict__ off,
                                                       int* __restrict__ bkst, int nblk,
                                                       int n, int total,
                                                       int* __restrict__ off_n,
                                                       int* __restrict__ bkst_n) {
    __shared__ int wsum[SC_TPB / 64];
    int bpref = 0;
    for (int i = 0; i < (int)blockIdx.x; ++i) bpref += bsum[i];  // uniform, <=64 iters
    int base = blockIdx.x * SC_TPB * SC_ITEMS;
    int tbase = base + threadIdx.x * SC_ITEMS;
    int loc[SC_ITEMS];
    int s = 0;
    for (int it = 0; it < SC_ITEMS; ++it) {
        int i = tbase + it;
        int v = (i < n) ? cnt[i] : 0;
        loc[it] = s;
        s += v;
    }
    int l = threadIdx.x & 63, wv = threadIdx.x >> 6;
    int inc = s;
    for (int d = 1; d < 64; d <<= 1) {
        int t = __shfl_up(inc, d);
        if (l >= d) inc += t;
    }
    int thr_ex = inc - s;
    if (l == 63) wsum[wv] = inc;
    __syncthreads();
    int woff = 0;
    for (int w = 0; w < wv; ++w) woff += wsum[w];
    int pref = bpref + woff + thr_ex;
    for (int it = 0; it < SC_ITEMS; ++it) {
        int i = tbase + it;
        if (i < n) {
            int val = pref + loc[it];
            off[i] = val;
            if (i % nblk == 0) bkst[i / nblk] = val;
        }
    }
    if (blockIdx.x == 0 && threadIdx.x == 0) { *off_n = total; *bkst_n = total; }
}

// ---------------- bucket pass 1: per-(bucket, block) counts, LDS histogram ----------------

__global__ __launch_bounds__(256) void k_bucket_count(const int* __restrict__ dst,
                                                      int* __restrict__ M,
                                                      int e, int nb, int nblk) {
    __shared__ int h[256];  // nb <= 256 (N <= 131072)
    for (int i = threadIdx.x; i < nb; i += 256) h[i] = 0;
    __syncthreads();
    int base = blockIdx.x * CH;
    int lim = min(base + CH, e);
    for (int i = base + threadIdx.x; i < lim; i += 256)
        atomicAdd(&h[dst[i] >> 9], 1);
    __syncthreads();
    for (int b = threadIdx.x; b < nb; b += 256)
        M[b * nblk + blockIdx.x] = h[b];
}

// ---------------- bucket pass 2: scatter packed edges into bucket regions ----------------
// packed: src (17 bits, N<=131072) | dst_local (9 bits) << 17

__global__ __launch_bounds__(256) void k_bucket_scatter(const int* __restrict__ src,
                                                        const int* __restrict__ dst,
                                                        const float* __restrict__ w,
                                                        const int* __restrict__ Ms,
                                                        int2* __restrict__ barr,
                                                        int e, int nb, int nblk) {
    __shared__ int cur[256];
    for (int i = threadIdx.x; i < nb; i += 256) cur[i] = Ms[i * nblk + blockIdx.x];
    __syncthreads();
    int base = blockIdx.x * CH;
    int lim = min(base + CH, e);
    for (int i = base + threadIdx.x; i < lim; i += 256) {
        int d = dst[i];
        int p = atomicAdd(&cur[d >> 9], 1);  // LDS cursor
        barr[p] = make_int2(src[i] | ((d & 511) << 17), __float_as_int(w[i]));
    }
}

// ---------------- bucket pass 3: per-bucket CSR build + degree/dis ----------------
// Emits ewn[p] = {src, w * dis[dst]} (int2); dis[src] folded in by k_finw.

__global__ __launch_bounds__(256) void k_csr_build(const int2* __restrict__ barr,
                                                   const int* __restrict__ bucketStart,
                                                   float* __restrict__ dis,
                                                   int* __restrict__ off,
                                                   int2* __restrict__ ewn, int n) {
    int b = blockIdx.x;
    int nbase = b << 9;
    int ebeg = bucketStart[b], eend = bucketStart[b + 1];
    __shared__ int cnt[BKT];
    __shared__ float wsum[BKT];
    __shared__ float disL[BKT];
    __shared__ int scn[BKT];
    __shared__ int wtot[4];

    for (int i = threadIdx.x; i < BKT; i += 256) { cnt[i] = 0; wsum[i] = 0.f; }
    __syncthreads();
    for (int j = ebeg + threadIdx.x; j < eend; j += 256) {
        int2 ed = barr[j];
        int dl = ed.x >> 17;
        atomicAdd(&cnt[dl], 1);
        atomicAdd(&wsum[dl], __int_as_float(ed.y));
    }
    __syncthreads();

    int t = threadIdx.x;
    int a0 = cnt[2 * t], a1 = cnt[2 * t + 1];
    int s = a0 + a1;
    int l = t & 63, wv = t >> 6;
    int inc = s;
    for (int d = 1; d < 64; d <<= 1) {
        int u = __shfl_up(inc, d);
        if (l >= d) inc += u;
    }
    if (l == 63) wtot[wv] = inc;
    for (int i = threadIdx.x; i < BKT; i += 256) {
        int node = nbase + i;
        if (node < n) {
            float dv = rsqrtf(1.0f + wsum[i]);  // deg = 1 (self-loop) + sum(w) > 0
            disL[i] = dv;
            dis[node] = dv;
        }
    }
    __syncthreads();
    int woff = 0;
    for (int k = 0; k < wv; ++k) woff += wtot[k];
    int ex = woff + inc - s;
    scn[2 * t] = ex;
    scn[2 * t + 1] = ex + a0;
    __syncthreads();
    for (int i = threadIdx.x; i < BKT; i += 256) {
        int node = nbase + i;
        if (node < n) off[node] = ebeg + scn[i];
    }
    __syncthreads();
    for (int j = ebeg + threadIdx.x; j < eend; j += 256) {
        int2 ed = barr[j];
        int dl = ed.x >> 17;
        int p = ebeg + atomicAdd(&scn[dl], 1);
        ewn[p] = make_int2(ed.x & 0x1FFFF,
                           __float_as_int(__int_as_float(ed.y) * disL[dl]));
    }
}

// fold dis[src] into the edge weight: ewn[i].y = w * dis[dst] * dis[src]
__global__ void k_finw(int2* __restrict__ ewn, const float* __restrict__ dis, int e) {
    int i = blockIdx.x * blockDim.x + threadIdx.x;
    if (i < e) {
        int2 v = ewn[i];
        ewn[i].y = __float_as_int(__int_as_float(v.y) * dis[v.x]);
    }
}

// ---------------- dense GEMM  Ybf16[n,C] = X[n,K] @ W[K,C]  (layer 1 only) ----------------

template <int K, int C>
__global__ __launch_bounds__(256) void k_gemm(const float* __restrict__ X,
                                              const float* __restrict__ W,
                                              unsigned short* __restrict__ Y, int n) {
    constexpr int CPT = 8;
    constexpr int CG = C / CPT;            // 8
    constexpr int RG = 256 / CG;           // 32
    constexpr int M = RG * 4;              // 128 rows per block
    constexpr int KC = (K > 64) ? 64 : K;  // K chunk
    constexpr int NKB = KC / 4;            // 16B k-blocks per chunk

    __shared__ float Ws[KC * C];
    __shared__ float Xs[M * KC];

    const int cg = threadIdx.x & (CG - 1);
    const int rg = threadIdx.x / CG;
    const int c0 = cg * CPT;
    const int r0 = rg * 4;
    const int base = blockIdx.x * M;

    float acc[4][CPT];
#pragma unroll
    for (int i = 0; i < 4; ++i)
#pragma unroll
        for (int j = 0; j < CPT; ++j) acc[i][j] = 0.f;

    for (int kc = 0; kc < K; kc += KC) {
        if (kc) __syncthreads();
        const float4* Wg4 = (const float4*)(W + (size_t)kc * C);
        for (int v = threadIdx.x; v < KC * C / 4; v += 256)
            ((float4*)Ws)[v] = Wg4[v];
        for (int v = threadIdx.x; v < M * NKB; v += 256) {
            int m = v / NKB, kb = v % NKB;
            int row = base + m;
            float4 val = make_float4(0.f, 0.f, 0.f, 0.f);
            if (row < n) val = *(const float4*)(X + (size_t)row * K + kc + kb * 4);
            *(float4*)&Xs[m * KC + ((kb ^ (m & 3)) << 2)] = val;
        }
        __syncthreads();

#pragma unroll 1
        for (int kb = 0; kb < NKB; ++kb) {
            const int k = kb * 4;
            float4 xv[4];
#pragma unroll
            for (int i = 0; i < 4; ++i)
                xv[i] = *(const float4*)&Xs[(r0 + i) * KC + ((kb ^ i) << 2)];
#pragma unroll
            for (int kk = 0; kk < 4; ++kk) {
                float4 wa = *(const float4*)&Ws[(k + kk) * C + c0];
                float4 wb = *(const float4*)&Ws[(k + kk) * C + c0 + 4];
#pragma unroll
                for (int i = 0; i < 4; ++i) {
                    float xk = ((const float*)&xv[i])[kk];
                    acc[i][0] = fmaf(xk, wa.x, acc[i][0]);
                    acc[i][1] = fmaf(xk, wa.y, acc[i][1]);
                    acc[i][2] = fmaf(xk, wa.z, acc[i][2]);
                    acc[i][3] = fmaf(xk, wa.w, acc[i][3]);
                    acc[i][4] = fmaf(xk, wb.x, acc[i][4]);
                    acc[i][5] = fmaf(xk, wb.y, acc[i][5]);
                    acc[i][6] = fmaf(xk, wb.z, acc[i][6]);
                    acc[i][7] = fmaf(xk, wb.w, acc[i][7]);
                }
            }
        }
    }

#pragma unroll
    for (int i = 0; i < 4; ++i) {
        int row = base + r0 + i;
        if (row < n) {
            uint4 o;
            o.x = (unsigned int)f2bf(acc[i][0]) | ((unsigned int)f2bf(acc[i][1]) << 16);
            o.y = (unsigned int)f2bf(acc[i][2]) | ((unsigned int)f2bf(acc[i][3]) << 16);
            o.z = (unsigned int)f2bf(acc[i][4]) | ((unsigned int)f2bf(acc[i][5]) << 16);
            o.w = (unsigned int)f2bf(acc[i][6]) | ((unsigned int)f2bf(acc[i][7]) << 16);
            *(uint4*)(Y + (size_t)row * C + c0) = o;
        }
    }
}

// ---------------- fused gather(64ch bf16) + relu + GEMM(64->CO) -> bf16 ----
// Block = 64 nodes. Phase 1: 16 quarter-waves (16 lanes), 4 nodes each.
// Edge list chunked by 16: lane l loads ewn[j0+l] (one coalesced 128B load =
// 16 edges), then the group iterates edges via __shfl broadcast -> all 16 row
// addresses available at once (MLP 16 vs 4, one ewn latency per 16 edges).
// Phase 2: 256 threads, rows {rg, rg+32} x CPT cols, W (fp32) staged in LDS.

template <int CO>
__global__ __launch_bounds__(256) void k_gg(const unsigned short* __restrict__ HW,
                                            const int* __restrict__ off,
                                            const int2* __restrict__ ewn,
                                            const float* __restrict__ dis,
                                            const float* __restrict__ bias,
                                            const float* __restrict__ W,
                                            unsigned short* __restrict__ Yout, int n) {
    __shared__ float Ys[64 * 64];
    __shared__ float Ws[64 * CO];

    const int base = blockIdx.x * 64;

    // stage W (64 x CO)
    for (int v = threadIdx.x; v < 64 * CO / 4; v += 256)
        ((float4*)Ws)[v] = ((const float4*)W)[v];

    // phase 1: 16 quarter-waves x 4 nodes, shfl-broadcast edge chunks of 16
    {
        const int qw = threadIdx.x >> 4;
        const int l = threadIdx.x & 15;
        const uint2* HW8 = (const uint2*)HW;   // 4 bf16 per uint2
        const float4 bb = ((const float4*)bias)[l];
#pragma unroll 1
        for (int p = 0; p < 4; ++p) {
            int m = qw * 4 + p;
            int node = base + m;
            if (node < n) {
                float dd = dis[node];
                uint2 hu = HW8[node * 16 + l];
                float4 A0, A1, A2, A3;
                A0.x = fmaf(dd * dd, bflo(hu.x), bb.x);
                A0.y = fmaf(dd * dd, bfhi(hu.x), bb.y);
                A0.z = fmaf(dd * dd, bflo(hu.y), bb.z);
                A0.w = fmaf(dd * dd, bfhi(hu.y), bb.w);
                A1 = make_float4(0.f, 0.f, 0.f, 0.f);
                A2 = A1; A3 = A1;
                int jbeg = off[node], jend = off[node + 1];
#pragma unroll 1
                for (int j0 = jbeg; j0 < jend; j0 += 16) {
                    int cnt = min(jend - j0, 16);
                    int2 my = make_int2(0, 0);
                    if (l < cnt) my = ewn[j0 + l];
                    int e = 0;
                    for (; e + 3 < cnt; e += 4) {
                        int s0 = __shfl(my.x, e, 16);
                        int s1 = __shfl(my.x, e + 1, 16);
                        int s2 = __shfl(my.x, e + 2, 16);
                        int s3 = __shfl(my.x, e + 3, 16);
                        float w0 = __int_as_float(__shfl(my.y, e, 16));
                        float w1 = __int_as_float(__shfl(my.y, e + 1, 16));
                        float w2 = __int_as_float(__shfl(my.y, e + 2, 16));
                        float w3 = __int_as_float(__shfl(my.y, e + 3, 16));
                        uint2 u0 = HW8[s0 * 16 + l];
                        uint2 u1 = HW8[s1 * 16 + l];
                        uint2 u2 = HW8[s2 * 16 + l];
                        uint2 u3 = HW8[s3 * 16 + l];
                        A0.x = fmaf(w0, bflo(u0.x), A0.x); A0.y = fmaf(w0, bfhi(u0.x), A0.y);
                        A0.z = fmaf(w0, bflo(u0.y), A0.z); A0.w = fmaf(w0, bfhi(u0.y), A0.w);
                        A1.x = fmaf(w1, bflo(u1.x), A1.x); A1.y = fmaf(w1, bfhi(u1.x), A1.y);
                        A1.z = fmaf(w1, bflo(u1.y), A1.z); A1.w = fmaf(w1, bfhi(u1.y), A1.w);
                        A2.x = fmaf(w2, bflo(u2.x), A2.x); A2.y = fmaf(w2, bfhi(u2.x), A2.y);
                        A2.z = fmaf(w2, bflo(u2.y), A2.z); A2.w = fmaf(w2, bfhi(u2.y), A2.w);
                        A3.x = fmaf(w3, bflo(u3.x), A3.x); A3.y = fmaf(w3, bfhi(u3.x), A3.y);
                        A3.z = fmaf(w3, bflo(u3.y), A3.z); A3.w = fmaf(w3, bfhi(u3.y), A3.w);
                    }
                    for (; e < cnt; ++e) {
                        int s0 = __shfl(my.x, e, 16);
                        float w0 = __int_as_float(__shfl(my.y, e, 16));
                        uint2 u0 = HW8[s0 * 16 + l];
                        A0.x = fmaf(w0, bflo(u0.x), A0.x); A0.y = fmaf(w0, bfhi(u0.x), A0.y);
                        A0.z = fmaf(w0, bflo(u0.y), A0.z); A0.w = fmaf(w0, bfhi(u0.y), A0.w);
                    }
                }
                float4 o;
                o.x = fmaxf((A0.x + A1.x) + (A2.x + A3.x), 0.f);
                o.y = fmaxf((A0.y + A1.y) + (A2.y + A3.y), 0.f);
                o.z = fmaxf((A0.z + A1.z) + (A2.z + A3.z), 0.f);
                o.w = fmaxf((A0.w + A1.w) + (A2.w + A3.w), 0.f);
                *(float4*)&Ys[m * 64 + ((l ^ (m & 7)) << 2)] = o;   // swizzled 16B block
            }
        }
    }
    __syncthreads();

    // phase 2: Yout[64][CO] (bf16) = Ys @ Ws ; thread tile = rows {rg, rg+32} x CPT
    constexpr int CPT = (CO == 32) ? 4 : 8;
    const int cg = threadIdx.x & 7;       // 8 col groups
    const int rg = threadIdx.x >> 3;      // 0..31
    const int c0 = cg * CPT;
    const int sw = rg & 7;                // row&7, same for rg and rg+32

    float acc[2][CPT];
#pragma unroll
    for (int i = 0; i < 2; ++i)
#pragma unroll
        for (int j = 0; j < CPT; ++j) acc[i][j] = 0.f;

#pragma unroll 1
    for (int kb = 0; kb < 16; ++kb) {
        const int k = kb * 4;
        float4 xv0 = *(const float4*)&Ys[rg * 64 + ((kb ^ sw) << 2)];
        float4 xv1 = *(const float4*)&Ys[(rg + 32) * 64 + ((kb ^ sw) << 2)];
#pragma unroll
        for (int kk = 0; kk < 4; ++kk) {
            float4 wa = *(const float4*)&Ws[(k + kk) * CO + c0];
            float4 wb;
            if constexpr (CPT == 8)
                wb = *(const float4*)&Ws[(k + kk) * CO + c0 + 4];
            float x0 = ((const float*)&xv0)[kk];
            float x1 = ((const float*)&xv1)[kk];
            acc[0][0] = fmaf(x0, wa.x, acc[0][0]); acc[1][0] = fmaf(x1, wa.x, acc[1][0]);
            acc[0][1] = fmaf(x0, wa.y, acc[0][1]); acc[1][1] = fmaf(x1, wa.y, acc[1][1]);
            acc[0][2] = fmaf(x0, wa.z, acc[0][2]); acc[1][2] = fmaf(x1, wa.z, acc[1][2]);
            acc[0][3] = fmaf(x0, wa.w, acc[0][3]); acc[1][3] = fmaf(x1, wa.w, acc[1][3]);
            if constexpr (CPT == 8) {
                acc[0][4] = fmaf(x0, wb.x, acc[0][4]); acc[1][4] = fmaf(x1, wb.x, acc[1][4]);
                acc[0][5] = fmaf(x0, wb.y, acc[0][5]); acc[1][5] = fmaf(x1, wb.y, acc[1][5]);
                acc[0][6] = fmaf(x0, wb.z, acc[0][6]); acc[1][6] = fmaf(x1, wb.z, acc[1][6]);
                acc[0][7] = fmaf(x0, wb.w, acc[0][7]); acc[1][7] = fmaf(x1, wb.w, acc[1][7]);
            }
        }
    }

#pragma unroll
    for (int i = 0; i < 2; ++i) {
        int row = base + rg + 32 * i;
        if (row < n) {
            if constexpr (CPT == 8) {
                uint4 o;
                o.x = (unsigned int)f2bf(acc[i][0]) | ((unsigned int)f2bf(acc[i][1]) << 16);
                o.y = (unsigned int)f2bf(acc[i][2]) | ((unsigned int)f2bf(acc[i][3]) << 16);
                o.z = (unsigned int)f2bf(acc[i][4]) | ((unsigned int)f2bf(acc[i][5]) << 16);
                o.w = (unsigned int)f2bf(acc[i][6]) | ((unsigned int)f2bf(acc[i][7]) << 16);
                *(uint4*)(Yout + (size_t)row * CO + c0) = o;
            } else {
                uint2 o;
                o.x = (unsigned int)f2bf(acc[i][0]) | ((unsigned int)f2bf(acc[i][1]) << 16);
                o.y = (unsigned int)f2bf(acc[i][2]) | ((unsigned int)f2bf(acc[i][3]) << 16);
                *(uint2*)(Yout + (size_t)row * CO + c0) = o;
            }
        }
    }
}

// ---------------- final CSR gather (32ch bf16 in, fp32 out), shfl-broadcast ----------------

__global__ __launch_bounds__(TPB) void k_gather32(const unsigned short* __restrict__ HW,
                                                  const int* __restrict__ off,
                                                  const int2* __restrict__ ewn,
                                                  const float* __restrict__ dis,
                                                  const float* __restrict__ b,
                                                  float* __restrict__ Y, int n) {
    int node = (blockIdx.x * blockDim.x + threadIdx.x) >> 4;
    int l = threadIdx.x & 15;
    if (node >= n) return;
    const unsigned int* HWu = (const unsigned int*)HW;  // 2 bf16 per uint
    float dd = dis[node];
    unsigned int hu = HWu[node * 16 + l];
    float2 bb = ((const float2*)b)[l];
    float a0x = fmaf(dd * dd, bflo(hu), bb.x);
    float a0y = fmaf(dd * dd, bfhi(hu), bb.y);
    float a1x = 0.f, a1y = 0.f, a2x = 0.f, a2y = 0.f, a3x = 0.f, a3y = 0.f;
    int jbeg = off[node], jend = off[node + 1];
#pragma unroll 1
    for (int j0 = jbeg; j0 < jend; j0 += 16) {
        int cnt = min(jend - j0, 16);
        int2 my = make_int2(0, 0);
        if (l < cnt) my = ewn[j0 + l];
        int e = 0;
        for (; e + 3 < cnt; e += 4) {
            int s0 = __shfl(my.x, e, 16);
            int s1 = __shfl(my.x, e + 1, 16);
            int s2 = __shfl(my.x, e + 2, 16);
            int s3 = __shfl(my.x, e + 3, 16);
            float w0 = __int_as_float(__shfl(my.y, e, 16));
            float w1 = __int_as_float(__shfl(my.y, e + 1, 16));
            float w2 = __int_as_float(__shfl(my.y, e + 2, 16));
            float w3 = __int_as_float(__shfl(my.y, e + 3, 16));
            unsigned int u0 = HWu[s0 * 16 + l];
            unsigned int u1 = HWu[s1 * 16 + l];
            unsigned int u2 = HWu[s2 * 16 + l];
            unsigned int u3 = HWu[s3 * 16 + l];
            a0x = fmaf(w0, bflo(u0), a0x); a0y = fmaf(w0, bfhi(u0), a0y);
            a1x = fmaf(w1, bflo(u1), a1x); a1y = fmaf(w1, bfhi(u1), a1y);
            a2x = fmaf(w2, bflo(u2), a2x); a2y = fmaf(w2, bfhi(u2), a2y);
            a3x = fmaf(w3, bflo(u3), a3x); a3y = fmaf(w3, bfhi(u3), a3y);
        }
        for (; e < cnt; ++e) {
            int s0 = __shfl(my.x, e, 16);
            float w0 = __int_as_float(__shfl(my.y, e, 16));
            unsigned int u0 = HWu[s0 * 16 + l];
            a0x = fmaf(w0, bflo(u0), a0x); a0y = fmaf(w0, bfhi(u0), a0y);
        }
    }
    float2 o;
    o.x = (a0x + a1x) + (a2x + a3x);
    o.y = (a0y + a1y) + (a2y + a3y);
    ((float2*)Y)[node * 16 + l] = o;
}

// ---------------- launch ----------------

extern "C" void kernel_launch(void* const* d_in, const int* in_sizes, int n_in,
                              void* d_out, int out_size, void* d_ws, size_t ws_size,
                              hipStream_t stream) {
    const float* x  = (const float*)d_in[0];
    const int*   ei = (const int*)d_in[1];
    const float* ew = (const float*)d_in[2];
    const float* W1 = (const float*)d_in[3];
    const float* b1 = (const float*)d_in[4];
    const float* W2 = (const float*)d_in[5];
    const float* b2 = (const float*)d_in[6];
    const float* W3 = (const float*)d_in[7];
    const float* b3 = (const float*)d_in[8];
    float* out = (float*)d_out;

    const int IN_C = 128, HID_C = 64;
    const int N = in_sizes[0] / IN_C;   // 100000 (< 2^17, required by packing)
    const int E = in_sizes[2];          // 1600000

    const int* src = ei;       // edge_index[0] = row (gather source)
    const int* dst = ei + E;   // edge_index[1] = col (destination)

    const int NB   = (N + BKT - 1) / BKT;        // 196 buckets (<=256 required)
    const int NBLK = (E + CH - 1) / CH;          // 196 chunk-blocks
    const int LM   = NB * NBLK;                  // count-matrix size

    // ---- workspace layout ----
    char* w = (char*)d_ws;
    float* dis   = (float*)w;                 w += sizeof(float) * N;
    int*   off   = (int*)w;                   w += sizeof(int) * (N + 1);
    int*   bkst  = (int*)w;                   w += sizeof(int) * (NB + 1);
    int*   bsum  = (int*)w;                   w += sizeof(int) * 64;
    w = (char*)(((size_t)w + 15) & ~(size_t)15);
    int2*  ewn   = (int2*)w;                  w += sizeof(int2) * E;
    // transient region: [M | barr] overlapped later by [A | B] (bf16 tables)
    char* w2 = (char*)(((size_t)w + 15) & ~(size_t)15);
    int*  M    = (int*)w2;
    int2* barr = (int2*)(((size_t)(M + LM) + 15) & ~(size_t)15);   // E int2
    unsigned short* A = (unsigned short*)w2;                        // N*64 bf16 (also A3: N*32)
    unsigned short* B = A + (size_t)N * HID_C;                      // N*64 bf16

    const int nScanM = (LM + SC_TPB * SC_ITEMS - 1) / (SC_TPB * SC_ITEMS);  // 19 <= 64

    // ---- build CSR + normalization (no global atomics) ----
    k_bucket_count<<<NBLK, 256, 0, stream>>>(dst, M, E, NB, NBLK);
    k_scan_blocks<<<nScanM, SC_TPB, 0, stream>>>(M, bsum, LM);
    k_scan_final<<<nScanM, SC_TPB, 0, stream>>>(M, bsum, M, bkst, NBLK, LM, E,
                                                off + N, bkst + NB);
    k_bucket_scatter<<<NBLK, 256, 0, stream>>>(src, dst, ew, M, barr, E, NB, NBLK);
    k_csr_build<<<NB, 256, 0, stream>>>(barr, bkst, dis, off, ewn, N);
    k_finw<<<(E + 255) / 256, 256, 0, stream>>>(ewn, dis, E);

    const int nT128 = (N + 127) / 128;
    const int nT64  = (N + 63) / 64;
    const int gQ    = (N * 16 + TPB - 1) / TPB;   // quarter-wave per node

    // ---- layer 1 GEMM: A = bf16(x @ W1) ----
    k_gemm<128, 64><<<nT128, 256, 0, stream>>>(x, W1, A, N);
    // ---- fused: B = bf16( relu(agg(A) + b1) @ W2 ) ----
    k_gg<64><<<nT64, 256, 0, stream>>>(A, off, ewn, dis, b1, W2, B, N);
    // ---- fused: A3 = bf16( relu(agg(B) + b2) @ W3 )  (A3 reuses A region, N*32) ----
    k_gg<32><<<nT64, 256, 0, stream>>>(B, off, ewn, dis, b2, W3, A, N);
    // ---- final: out = agg(A3) + b3  (fp32) ----
    k_gather32<<<gQ, TPB, 0, stream>>>(A, off, ewn, dis, b3, out, N);
}

// Round 16
// 283.816 us; speedup vs baseline: 1.4433x; 1.0267x over previous
//
#include <hip/hip_runtime.h>
#include <math.h>

#define TPB 256
#define SC_TPB 256
#define SC_ITEMS 8   // 2048 elements per scan block
#define CH 8192      // edges per bucket-pass block
#define BKT 512      // nodes per bucket (bucket = dst >> 9)

// ---------------- bf16 helpers (storage only; all math fp32) ----------------

__device__ __forceinline__ unsigned short f2bf(float f) {   // RNE
    unsigned int u = __float_as_uint(f);
    unsigned int r = u + 0x7FFFu + ((u >> 16) & 1u);
    return (unsigned short)(r >> 16);
}
__device__ __forceinline__ float bflo(unsigned int u) { return __uint_as_float(u << 16); }
__device__ __forceinline__ float bfhi(unsigned int u) { return __uint_as_float(u & 0xFFFF0000u); }

// accumulate 8 bf16 channels (uint4) into two float4 accumulators
__device__ __forceinline__ void acc8(float4& pa, float4& pb, float wt, uint4 uv) {
    pa.x = fmaf(wt, bflo(uv.x), pa.x); pa.y = fmaf(wt, bfhi(uv.x), pa.y);
    pa.z = fmaf(wt, bflo(uv.y), pa.z); pa.w = fmaf(wt, bfhi(uv.y), pa.w);
    pb.x = fmaf(wt, bflo(uv.z), pb.x); pb.y = fmaf(wt, bfhi(uv.z), pb.y);
    pb.z = fmaf(wt, bflo(uv.w), pb.z); pb.w = fmaf(wt, bfhi(uv.w), pb.w);
}
// accumulate 4 bf16 channels (uint2) into one float4 accumulator
__device__ __forceinline__ void acc4(float4& pa, float wt, uint2 uv) {
    pa.x = fmaf(wt, bflo(uv.x), pa.x); pa.y = fmaf(wt, bfhi(uv.x), pa.y);
    pa.z = fmaf(wt, bflo(uv.y), pa.z); pa.w = fmaf(wt, bfhi(uv.y), pa.w);
}

// ---------------- multi-block exclusive scan (2 kernels) ----------------

__global__ __launch_bounds__(SC_TPB) void k_scan_blocks(const int* __restrict__ cnt,
                                                        int* __restrict__ bsum, int n) {
    __shared__ int red[SC_TPB / 64];
    int base = blockIdx.x * SC_TPB * SC_ITEMS;
    int s = 0;
    for (int it = 0; it < SC_ITEMS; ++it) {
        int i = base + it * SC_TPB + threadIdx.x;
        if (i < n) s += cnt[i];
    }
    for (int d = 1; d < 64; d <<= 1) s += __shfl_xor(s, d);
    if ((threadIdx.x & 63) == 0) red[threadIdx.x >> 6] = s;
    __syncthreads();
    if (threadIdx.x == 0) {
        int t = 0;
        for (int w = 0; w < SC_TPB / 64; ++w) t += red[w];
        bsum[blockIdx.x] = t;
    }
}

// final scan pass; computes its own block-prefix from raw bsum (<=64 entries);
// emits bkst[b] = scanned[b*nblk]; block 0 writes off[N]=E, bkst[NB]=E.
__global__ __launch_bounds__(SC_TPB) void k_scan_final(const int* __restrict__ cnt,
                                                       const int* __restrict__ bsum,
                                                       int* __restrict__ off,
                                                       int* __restrict__ bkst, int nblk,
                                                       int n, int total,
                                                       int* __restrict__ off_n,
                                                       int* __restrict__ bkst_n) {
    __shared__ int wsum[SC_TPB / 64];
    int bpref = 0;
    for (int i = 0; i < (int)blockIdx.x; ++i) bpref += bsum[i];  // uniform, <=64 iters
    int base = blockIdx.x * SC_TPB * SC_ITEMS;
    int tbase = base + threadIdx.x * SC_ITEMS;
    int loc[SC_ITEMS];
    int s = 0;
    for (int it = 0; it < SC_ITEMS; ++it) {
        int i = tbase + it;
        int v = (i < n) ? cnt[i] : 0;
        loc[it] = s;
        s += v;
    }
    int l = threadIdx.x & 63, wv = threadIdx.x >> 6;
    int inc = s;
    for (int d = 1; d < 64; d <<= 1) {
        int t = __shfl_up(inc, d);
        if (l >= d) inc += t;
    }
    int thr_ex = inc - s;
    if (l == 63) wsum[wv] = inc;
    __syncthreads();
    int woff = 0;
    for (int w = 0; w < wv; ++w) woff += wsum[w];
    int pref = bpref + woff + thr_ex;
    for (int it = 0; it < SC_ITEMS; ++it) {
        int i = tbase + it;
        if (i < n) {
            int val = pref + loc[it];
            off[i] = val;
            if (i % nblk == 0) bkst[i / nblk] = val;
        }
    }
    if (blockIdx.x == 0 && threadIdx.x == 0) { *off_n = total; *bkst_n = total; }
}

// ---------------- bucket pass 1: per-(bucket, block) counts, LDS histogram ----------------

__global__ __launch_bounds__(256) void k_bucket_count(const int* __restrict__ dst,
                                                      int* __restrict__ M,
                                                      int e, int nb, int nblk) {
    __shared__ int h[256];  // nb <= 256 (N <= 131072)
    for (int i = threadIdx.x; i < nb; i += 256) h[i] = 0;
    __syncthreads();
    int base = blockIdx.x * CH;
    int lim = min(base + CH, e);
    for (int i = base + threadIdx.x; i < lim; i += 256)
        atomicAdd(&h[dst[i] >> 9], 1);
    __syncthreads();
    for (int b = threadIdx.x; b < nb; b += 256)
        M[b * nblk + blockIdx.x] = h[b];
}

// ---------------- bucket pass 2: scatter packed edges into bucket regions ----------------
// packed: src (17 bits, N<=131072) | dst_local (9 bits) << 17

__global__ __launch_bounds__(256) void k_bucket_scatter(const int* __restrict__ src,
                                                        const int* __restrict__ dst,
                                                        const float* __restrict__ w,
                                                        const int* __restrict__ Ms,
                                                        int2* __restrict__ barr,
                                                        int e, int nb, int nblk) {
    __shared__ int cur[256];
    for (int i = threadIdx.x; i < nb; i += 256) cur[i] = Ms[i * nblk + blockIdx.x];
    __syncthreads();
    int base = blockIdx.x * CH;
    int lim = min(base + CH, e);
    for (int i = base + threadIdx.x; i < lim; i += 256) {
        int d = dst[i];
        int p = atomicAdd(&cur[d >> 9], 1);  // LDS cursor
        barr[p] = make_int2(src[i] | ((d & 511) << 17), __float_as_int(w[i]));
    }
}

// ---------------- bucket pass 3: per-bucket CSR build + degree/dis ----------------
// Emits ewn[p] = {src, w * dis[dst]} (int2); dis[src] folded in by k_finw.

__global__ __launch_bounds__(256) void k_csr_build(const int2* __restrict__ barr,
                                                   const int* __restrict__ bucketStart,
                                                   float* __restrict__ dis,
                                                   int* __restrict__ off,
                                                   int2* __restrict__ ewn, int n) {
    int b = blockIdx.x;
    int nbase = b << 9;
    int ebeg = bucketStart[b], eend = bucketStart[b + 1];
    __shared__ int cnt[BKT];
    __shared__ float wsum[BKT];
    __shared__ float disL[BKT];
    __shared__ int scn[BKT];
    __shared__ int wtot[4];

    for (int i = threadIdx.x; i < BKT; i += 256) { cnt[i] = 0; wsum[i] = 0.f; }
    __syncthreads();
    for (int j = ebeg + threadIdx.x; j < eend; j += 256) {
        int2 ed = barr[j];
        int dl = ed.x >> 17;
        atomicAdd(&cnt[dl], 1);
        atomicAdd(&wsum[dl], __int_as_float(ed.y));
    }
    __syncthreads();

    int t = threadIdx.x;
    int a0 = cnt[2 * t], a1 = cnt[2 * t + 1];
    int s = a0 + a1;
    int l = t & 63, wv = t >> 6;
    int inc = s;
    for (int d = 1; d < 64; d <<= 1) {
        int u = __shfl_up(inc, d);
        if (l >= d) inc += u;
    }
    if (l == 63) wtot[wv] = inc;
    for (int i = threadIdx.x; i < BKT; i += 256) {
        int node = nbase + i;
        if (node < n) {
            float dv = rsqrtf(1.0f + wsum[i]);  // deg = 1 (self-loop) + sum(w) > 0
            disL[i] = dv;
            dis[node] = dv;
        }
    }
    __syncthreads();
    int woff = 0;
    for (int k = 0; k < wv; ++k) woff += wtot[k];
    int ex = woff + inc - s;
    scn[2 * t] = ex;
    scn[2 * t + 1] = ex + a0;
    __syncthreads();
    for (int i = threadIdx.x; i < BKT; i += 256) {
        int node = nbase + i;
        if (node < n) off[node] = ebeg + scn[i];
    }
    __syncthreads();
    for (int j = ebeg + threadIdx.x; j < eend; j += 256) {
        int2 ed = barr[j];
        int dl = ed.x >> 17;
        int p = ebeg + atomicAdd(&scn[dl], 1);
        ewn[p] = make_int2(ed.x & 0x1FFFF,
                           __float_as_int(__int_as_float(ed.y) * disL[dl]));
    }
}

// fold dis[src] into the edge weight: ewn[i].y = w * dis[dst] * dis[src]
__global__ void k_finw(int2* __restrict__ ewn, const float* __restrict__ dis, int e) {
    int i = blockIdx.x * blockDim.x + threadIdx.x;
    if (i < e) {
        int2 v = ewn[i];
        ewn[i].y = __float_as_int(__int_as_float(v.y) * dis[v.x]);
    }
}

// ---------------- dense GEMM  Ybf16[n,C] = X[n,K] @ W[K,C]  (layer 1 only) ----------------

template <int K, int C>
__global__ __launch_bounds__(256) void k_gemm(const float* __restrict__ X,
                                              const float* __restrict__ W,
                                              unsigned short* __restrict__ Y, int n) {
    constexpr int CPT = 8;
    constexpr int CG = C / CPT;            // 8
    constexpr int RG = 256 / CG;           // 32
    constexpr int M = RG * 4;              // 128 rows per block
    constexpr int KC = (K > 64) ? 64 : K;  // K chunk
    constexpr int NKB = KC / 4;            // 16B k-blocks per chunk

    __shared__ float Ws[KC * C];
    __shared__ float Xs[M * KC];

    const int cg = threadIdx.x & (CG - 1);
    const int rg = threadIdx.x / CG;
    const int c0 = cg * CPT;
    const int r0 = rg * 4;
    const int base = blockIdx.x * M;

    float acc[4][CPT];
#pragma unroll
    for (int i = 0; i < 4; ++i)
#pragma unroll
        for (int j = 0; j < CPT; ++j) acc[i][j] = 0.f;

    for (int kc = 0; kc < K; kc += KC) {
        if (kc) __syncthreads();
        const float4* Wg4 = (const float4*)(W + (size_t)kc * C);
        for (int v = threadIdx.x; v < KC * C / 4; v += 256)
            ((float4*)Ws)[v] = Wg4[v];
        for (int v = threadIdx.x; v < M * NKB; v += 256) {
            int m = v / NKB, kb = v % NKB;
            int row = base + m;
            float4 val = make_float4(0.f, 0.f, 0.f, 0.f);
            if (row < n) val = *(const float4*)(X + (size_t)row * K + kc + kb * 4);
            *(float4*)&Xs[m * KC + ((kb ^ (m & 3)) << 2)] = val;
        }
        __syncthreads();

#pragma unroll 1
        for (int kb = 0; kb < NKB; ++kb) {
            const int k = kb * 4;
            float4 xv[4];
#pragma unroll
            for (int i = 0; i < 4; ++i)
                xv[i] = *(const float4*)&Xs[(r0 + i) * KC + ((kb ^ i) << 2)];
#pragma unroll
            for (int kk = 0; kk < 4; ++kk) {
                float4 wa = *(const float4*)&Ws[(k + kk) * C + c0];
                float4 wb = *(const float4*)&Ws[(k + kk) * C + c0 + 4];
#pragma unroll
                for (int i = 0; i < 4; ++i) {
                    float xk = ((const float*)&xv[i])[kk];
                    acc[i][0] = fmaf(xk, wa.x, acc[i][0]);
                    acc[i][1] = fmaf(xk, wa.y, acc[i][1]);
                    acc[i][2] = fmaf(xk, wa.z, acc[i][2]);
                    acc[i][3] = fmaf(xk, wa.w, acc[i][3]);
                    acc[i][4] = fmaf(xk, wb.x, acc[i][4]);
                    acc[i][5] = fmaf(xk, wb.y, acc[i][5]);
                    acc[i][6] = fmaf(xk, wb.z, acc[i][6]);
                    acc[i][7] = fmaf(xk, wb.w, acc[i][7]);
                }
            }
        }
    }

#pragma unroll
    for (int i = 0; i < 4; ++i) {
        int row = base + r0 + i;
        if (row < n) {
            uint4 o;
            o.x = (unsigned int)f2bf(acc[i][0]) | ((unsigned int)f2bf(acc[i][1]) << 16);
            o.y = (unsigned int)f2bf(acc[i][2]) | ((unsigned int)f2bf(acc[i][3]) << 16);
            o.z = (unsigned int)f2bf(acc[i][4]) | ((unsigned int)f2bf(acc[i][5]) << 16);
            o.w = (unsigned int)f2bf(acc[i][6]) | ((unsigned int)f2bf(acc[i][7]) << 16);
            *(uint4*)(Y + (size_t)row * C + c0) = o;
        }
    }
}

// ---------------- fused gather(64ch bf16) + relu + GEMM(64->CO) -> bf16 ----
// Block = 64 nodes. Phase 1: 32 eighth-waves (8 lanes x uint4 = 16B/lane,
// 128B/row = one request), 2 nodes each; 8-deep preloaded edge batches
// (s[8] -> u[8] loads -> FMAs) = up to 64 outstanding row loads per wave.
// Phase 2: 256 threads, rows {rg, rg+32} x CPT cols, W (fp32) staged in LDS.

template <int CO>
__global__ __launch_bounds__(256) void k_gg(const unsigned short* __restrict__ HW,
                                            const int* __restrict__ off,
                                            const int2* __restrict__ ewn,
                                            const float* __restrict__ dis,
                                            const float* __restrict__ bias,
                                            const float* __restrict__ W,
                                            unsigned short* __restrict__ Yout, int n) {
    __shared__ float Ys[64 * 64];
    __shared__ float Ws[64 * CO];

    const int base = blockIdx.x * 64;

    // stage W (64 x CO)
    for (int v = threadIdx.x; v < 64 * CO / 4; v += 256)
        ((float4*)Ws)[v] = ((const float4*)W)[v];

    // phase 1: 32 eighth-waves x 2 nodes, 8-deep preloaded edge batches
    {
        const int g = threadIdx.x >> 3;     // 0..31
        const int l = threadIdx.x & 7;      // lane in group; channels l*8..l*8+7
        const uint4* HW16 = (const uint4*)HW;   // 8 bf16 per uint4; row = 8 uint4
        const float4 bb0 = ((const float4*)bias)[2 * l];
        const float4 bb1 = ((const float4*)bias)[2 * l + 1];
#pragma unroll 1
        for (int p = 0; p < 2; ++p) {
            int m = g * 2 + p;
            int node = base + m;
            if (node < n) {
                float dd = dis[node];
                float d2 = dd * dd;
                uint4 hu = HW16[(size_t)node * 8 + l];
                float4 A0, A1, B0, B1;
                A0.x = fmaf(d2, bflo(hu.x), bb0.x); A0.y = fmaf(d2, bfhi(hu.x), bb0.y);
                A0.z = fmaf(d2, bflo(hu.y), bb0.z); A0.w = fmaf(d2, bfhi(hu.y), bb0.w);
                A1.x = fmaf(d2, bflo(hu.z), bb1.x); A1.y = fmaf(d2, bfhi(hu.z), bb1.y);
                A1.z = fmaf(d2, bflo(hu.w), bb1.z); A1.w = fmaf(d2, bfhi(hu.w), bb1.w);
                B0 = make_float4(0.f, 0.f, 0.f, 0.f);
                B1 = B0;
                int jbeg = off[node], jend = off[node + 1];
#pragma unroll 1
                for (int j0 = jbeg; j0 < jend; j0 += 8) {
                    int cnt = min(jend - j0, 8);
                    int2 my = make_int2(0, 0);
                    if (l < cnt) my = ewn[j0 + l];
                    if (cnt == 8) {
                        int sidx[8];
#pragma unroll
                        for (int e = 0; e < 8; ++e) sidx[e] = __shfl(my.x, e, 8);
                        uint4 u[8];
#pragma unroll
                        for (int e = 0; e < 8; ++e) u[e] = HW16[(size_t)sidx[e] * 8 + l];
#pragma unroll
                        for (int e = 0; e < 8; ++e) {
                            float wt = __int_as_float(__shfl(my.y, e, 8));
                            if (e & 1) acc8(B0, B1, wt, u[e]);
                            else       acc8(A0, A1, wt, u[e]);
                        }
                    } else {
                        for (int e = 0; e < cnt; ++e) {
                            int s0 = __shfl(my.x, e, 8);
                            float wt = __int_as_float(__shfl(my.y, e, 8));
                            uint4 u0 = HW16[(size_t)s0 * 8 + l];
                            acc8(A0, A1, wt, u0);
                        }
                    }
                }
                float4 o0, o1;
                o0.x = fmaxf(A0.x + B0.x, 0.f); o0.y = fmaxf(A0.y + B0.y, 0.f);
                o0.z = fmaxf(A0.z + B0.z, 0.f); o0.w = fmaxf(A0.w + B0.w, 0.f);
                o1.x = fmaxf(A1.x + B1.x, 0.f); o1.y = fmaxf(A1.y + B1.y, 0.f);
                o1.z = fmaxf(A1.z + B1.z, 0.f); o1.w = fmaxf(A1.w + B1.w, 0.f);
                // swizzled 16B blocks: block b stored at b ^ (m&7)
                *(float4*)&Ys[m * 64 + (((2 * l) ^ (m & 7)) << 2)] = o0;
                *(float4*)&Ys[m * 64 + (((2 * l + 1) ^ (m & 7)) << 2)] = o1;
            }
        }
    }
    __syncthreads();

    // phase 2: Yout[64][CO] (bf16) = Ys @ Ws ; thread tile = rows {rg, rg+32} x CPT
    constexpr int CPT = (CO == 32) ? 4 : 8;
    const int cg = threadIdx.x & 7;       // 8 col groups
    const int rg = threadIdx.x >> 3;      // 0..31
    const int c0 = cg * CPT;
    const int sw = rg & 7;                // row&7, same for rg and rg+32

    float acc[2][CPT];
#pragma unroll
    for (int i = 0; i < 2; ++i)
#pragma unroll
        for (int j = 0; j < CPT; ++j) acc[i][j] = 0.f;

#pragma unroll 1
    for (int kb = 0; kb < 16; ++kb) {
        const int k = kb * 4;
        float4 xv0 = *(const float4*)&Ys[rg * 64 + ((kb ^ sw) << 2)];
        float4 xv1 = *(const float4*)&Ys[(rg + 32) * 64 + ((kb ^ sw) << 2)];
#pragma unroll
        for (int kk = 0; kk < 4; ++kk) {
            float4 wa = *(const float4*)&Ws[(k + kk) * CO + c0];
            float4 wb;
            if constexpr (CPT == 8)
                wb = *(const float4*)&Ws[(k + kk) * CO + c0 + 4];
            float x0 = ((const float*)&xv0)[kk];
            float x1 = ((const float*)&xv1)[kk];
            acc[0][0] = fmaf(x0, wa.x, acc[0][0]); acc[1][0] = fmaf(x1, wa.x, acc[1][0]);
            acc[0][1] = fmaf(x0, wa.y, acc[0][1]); acc[1][1] = fmaf(x1, wa.y, acc[1][1]);
            acc[0][2] = fmaf(x0, wa.z, acc[0][2]); acc[1][2] = fmaf(x1, wa.z, acc[1][2]);
            acc[0][3] = fmaf(x0, wa.w, acc[0][3]); acc[1][3] = fmaf(x1, wa.w, acc[1][3]);
            if constexpr (CPT == 8) {
                acc[0][4] = fmaf(x0, wb.x, acc[0][4]); acc[1][4] = fmaf(x1, wb.x, acc[1][4]);
                acc[0][5] = fmaf(x0, wb.y, acc[0][5]); acc[1][5] = fmaf(x1, wb.y, acc[1][5]);
                acc[0][6] = fmaf(x0, wb.z, acc[0][6]); acc[1][6] = fmaf(x1, wb.z, acc[1][6]);
                acc[0][7] = fmaf(x0, wb.w, acc[0][7]); acc[1][7] = fmaf(x1, wb.w, acc[1][7]);
            }
        }
    }

#pragma unroll
    for (int i = 0; i < 2; ++i) {
        int row = base + rg + 32 * i;
        if (row < n) {
            if constexpr (CPT == 8) {
                uint4 o;
                o.x = (unsigned int)f2bf(acc[i][0]) | ((unsigned int)f2bf(acc[i][1]) << 16);
                o.y = (unsigned int)f2bf(acc[i][2]) | ((unsigned int)f2bf(acc[i][3]) << 16);
                o.z = (unsigned int)f2bf(acc[i][4]) | ((unsigned int)f2bf(acc[i][5]) << 16);
                o.w = (unsigned int)f2bf(acc[i][6]) | ((unsigned int)f2bf(acc[i][7]) << 16);
                *(uint4*)(Yout + (size_t)row * CO + c0) = o;
            } else {
                uint2 o;
                o.x = (unsigned int)f2bf(acc[i][0]) | ((unsigned int)f2bf(acc[i][1]) << 16);
                o.y = (unsigned int)f2bf(acc[i][2]) | ((unsigned int)f2bf(acc[i][3]) << 16);
                *(uint2*)(Yout + (size_t)row * CO + c0) = o;
            }
        }
    }
}

// ---------------- final CSR gather (32ch bf16 in, fp32 out), eighth-wave 8-deep ----------------

__global__ __launch_bounds__(TPB) void k_gather32(const unsigned short* __restrict__ HW,
                                                  const int* __restrict__ off,
                                                  const int2* __restrict__ ewn,
                                                  const float* __restrict__ dis,
                                                  const float* __restrict__ b,
                                                  float* __restrict__ Y, int n) {
    int node = (blockIdx.x * blockDim.x + threadIdx.x) >> 3;
    int l = threadIdx.x & 7;                 // channels l*4..l*4+3
    if (node >= n) return;
    const uint2* HW8 = (const uint2*)HW;     // 4 bf16 per uint2; row = 8 uint2 (64B)
    float dd = dis[node];
    float d2 = dd * dd;
    uint2 hu = HW8[(size_t)node * 8 + l];
    float4 bb = ((const float4*)b)[l];
    float4 A, B;
    A.x = fmaf(d2, bflo(hu.x), bb.x); A.y = fmaf(d2, bfhi(hu.x), bb.y);
    A.z = fmaf(d2, bflo(hu.y), bb.z); A.w = fmaf(d2, bfhi(hu.y), bb.w);
    B = make_float4(0.f, 0.f, 0.f, 0.f);
    int jbeg = off[node], jend = off[node + 1];
#pragma unroll 1
    for (int j0 = jbeg; j0 < jend; j0 += 8) {
        int cnt = min(jend - j0, 8);
        int2 my = make_int2(0, 0);
        if (l < cnt) my = ewn[j0 + l];
        if (cnt == 8) {
            int sidx[8];
#pragma unroll
            for (int e = 0; e < 8; ++e) sidx[e] = __shfl(my.x, e, 8);
            uint2 u[8];
#pragma unroll
            for (int e = 0; e < 8; ++e) u[e] = HW8[(size_t)sidx[e] * 8 + l];
#pragma unroll
            for (int e = 0; e < 8; ++e) {
                float wt = __int_as_float(__shfl(my.y, e, 8));
                if (e & 1) acc4(B, wt, u[e]);
                else       acc4(A, wt, u[e]);
            }
        } else {
            for (int e = 0; e < cnt; ++e) {
                int s0 = __shfl(my.x, e, 8);
                float wt = __int_as_float(__shfl(my.y, e, 8));
                uint2 u0 = HW8[(size_t)s0 * 8 + l];
                acc4(A, wt, u0);
            }
        }
    }
    float4 o;
    o.x = A.x + B.x; o.y = A.y + B.y; o.z = A.z + B.z; o.w = A.w + B.w;
    *(float4*)(Y + (size_t)node * 32 + l * 4) = o;
}

// ---------------- launch ----------------

extern "C" void kernel_launch(void* const* d_in, const int* in_sizes, int n_in,
                              void* d_out, int out_size, void* d_ws, size_t ws_size,
                              hipStream_t stream) {
    const float* x  = (const float*)d_in[0];
    const int*   ei = (const int*)d_in[1];
    const float* ew = (const float*)d_in[2];
    const float* W1 = (const float*)d_in[3];
    const float* b1 = (const float*)d_in[4];
    const float* W2 = (const float*)d_in[5];
    const float* b2 = (const float*)d_in[6];
    const float* W3 = (const float*)d_in[7];
    const float* b3 = (const float*)d_in[8];
    float* out = (float*)d_out;

    const int IN_C = 128, HID_C = 64;
    const int N = in_sizes[0] / IN_C;   // 100000 (< 2^17, required by packing)
    const int E = in_sizes[2];          // 1600000

    const int* src = ei;       // edge_index[0] = row (gather source)
    const int* dst = ei + E;   // edge_index[1] = col (destination)

    const int NB   = (N + BKT - 1) / BKT;        // 196 buckets (<=256 required)
    const int NBLK = (E + CH - 1) / CH;          // 196 chunk-blocks
    const int LM   = NB * NBLK;                  // count-matrix size

    // ---- workspace layout ----
    char* w = (char*)d_ws;
    float* dis   = (float*)w;                 w += sizeof(float) * N;
    int*   off   = (int*)w;                   w += sizeof(int) * (N + 1);
    int*   bkst  = (int*)w;                   w += sizeof(int) * (NB + 1);
    int*   bsum  = (int*)w;                   w += sizeof(int) * 64;
    w = (char*)(((size_t)w + 15) & ~(size_t)15);
    int2*  ewn   = (int2*)w;                  w += sizeof(int2) * E;
    // transient region: [M | barr] overlapped later by [A | B] (bf16 tables)
    char* w2 = (char*)(((size_t)w + 15) & ~(size_t)15);
    int*  M    = (int*)w2;
    int2* barr = (int2*)(((size_t)(M + LM) + 15) & ~(size_t)15);   // E int2
    unsigned short* A = (unsigned short*)w2;                        // N*64 bf16 (also A3: N*32)
    unsigned short* B = A + (size_t)N * HID_C;                      // N*64 bf16

    const int nScanM = (LM + SC_TPB * SC_ITEMS - 1) / (SC_TPB * SC_ITEMS);  // 19 <= 64

    // ---- build CSR + normalization (no global atomics) ----
    k_bucket_count<<<NBLK, 256, 0, stream>>>(dst, M, E, NB, NBLK);
    k_scan_blocks<<<nScanM, SC_TPB, 0, stream>>>(M, bsum, LM);
    k_scan_final<<<nScanM, SC_TPB, 0, stream>>>(M, bsum, M, bkst, NBLK, LM, E,
                                                off + N, bkst + NB);
    k_bucket_scatter<<<NBLK, 256, 0, stream>>>(src, dst, ew, M, barr, E, NB, NBLK);
    k_csr_build<<<NB, 256, 0, stream>>>(barr, bkst, dis, off, ewn, N);
    k_finw<<<(E + 255) / 256, 256, 0, stream>>>(ewn, dis, E);

    const int nT128 = (N + 127) / 128;
    const int nT64  = (N + 63) / 64;
    const int gE8   = (N * 8 + TPB - 1) / TPB;   // eighth-wave per node

    // ---- layer 1 GEMM: A = bf16(x @ W1) ----
    k_gemm<128, 64><<<nT128, 256, 0, stream>>>(x, W1, A, N);
    // ---- fused: B = bf16( relu(agg(A) + b1) @ W2 ) ----
    k_gg<64><<<nT64, 256, 0, stream>>>(A, off, ewn, dis, b1, W2, B, N);
    // ---- fused: A3 = bf16( relu(agg(B) + b2) @ W3 )  (A3 reuses A region, N*32) ----
    k_gg<32><<<nT64, 256, 0, stream>>>(B, off, ewn, dis, b2, W3, A, N);
    // ---- final: out = agg(A3) + b3  (fp32) ----
    k_gather32<<<gE8, TPB, 0, stream>>>(A, off, ewn, dis, b3, out, N);
}